// Round 1
// baseline (7760.368 us; speedup 1.0000x reference)
//
#include <hip/hip_runtime.h>

#define NN 50000
#define EE 800000
#define GG 128
#define LL 4
#define EB 8   // edges per wave in edge kernel

__device__ __forceinline__ float silu_f(float x){
    return x / (1.0f + __expf(-x));
}
// order-preserving float<->uint encoding for atomicMax on floats
__device__ __forceinline__ unsigned fenc(float v){
    unsigned u = __float_as_uint(v);
    return (u & 0x80000000u) ? ~u : (u | 0x80000000u);
}
__device__ __forceinline__ float fdec(unsigned u){
    return (u & 0x80000000u) ? __uint_as_float(u & 0x7fffffffu) : __uint_as_float(~u);
}

// f = silu(x @ W + b), one wave per node
__global__ __launch_bounds__(256) void input_mlp(const float* __restrict__ x,
        const float* __restrict__ Wg, const float* __restrict__ bg,
        float* __restrict__ f, int N){
    __shared__ __align__(16) float sW[64*64];
    __shared__ float sb[64];
    __shared__ __align__(16) float srow[4][64];
    int tid=threadIdx.x, wid=tid>>6, lane=tid&63;
    for(int i=tid;i<4096;i+=256) sW[i]=Wg[i];
    if(tid<64) sb[tid]=bg[tid];
    __syncthreads();
    int gw=gridDim.x*4;
    int n0=blockIdx.x*4+wid;
    int niter=(N+gw-1)/gw;
    for(int it=0;it<niter;++it){
        int n=n0+it*gw; bool act = n<N;
        if(act) srow[wid][lane]=x[n*64+lane];
        __syncthreads();
        if(act){
            float h=sb[lane];
            #pragma unroll
            for(int k=0;k<64;k+=4){
                float4 m4=*(const float4*)&srow[wid][k];
                h += m4.x*sW[k*64+lane] + m4.y*sW[(k+1)*64+lane]
                   + m4.z*sW[(k+2)*64+lane] + m4.w*sW[(k+3)*64+lane];
            }
            f[n*64+lane]=silu_f(h);
        }
        __syncthreads();
    }
}

// Edge message MLP: mi=[f[src],f[dst],w^2] (129) -> silu -> (64) -> silu -> silu -> atomic scatter to msum[dst]
__global__ __launch_bounds__(256) void edge_msg(const float* __restrict__ f,
        const int* __restrict__ src, const int* __restrict__ dst, const float* __restrict__ w,
        const float* __restrict__ W1g, const float* __restrict__ b1g,
        const float* __restrict__ W2g, const float* __restrict__ b2g,
        float* __restrict__ msum, int E){
    __shared__ __align__(16) float sW1[129*64];   // 33 KB
    __shared__ __align__(16) float sW2[64*64];    // 16 KB
    __shared__ float sb1[64], sb2[64];
    __shared__ __align__(16) float smi[4][EB][132]; // 16.9 KB
    __shared__ __align__(16) float sh1[4][EB][64];  // 8 KB   => ~75 KB total, 2 blocks/CU
    int tid=threadIdx.x, wid=tid>>6, lane=tid&63;
    for(int i=tid;i<129*64;i+=256) sW1[i]=W1g[i];
    for(int i=tid;i<64*64;i+=256)  sW2[i]=W2g[i];
    if(tid<64){ sb1[tid]=b1g[tid]; sb2[tid]=b2g[tid]; }
    __syncthreads();
    int gw=gridDim.x*4;                 // total waves
    int n0=blockIdx.x*4+wid;            // this wave's batch index base
    int nbatch=(E + EB*gw - 1)/(EB*gw);
    for(int it=0;it<nbatch;++it){
        int ebase=(n0 + it*gw)*EB;
        int dsts[EB];
        #pragma unroll
        for(int e=0;e<EB;++e){
            int ei=ebase+e;
            dsts[e]=-1;
            if(ei<E){
                int s=src[ei]; int d=dst[ei]; dsts[e]=d;
                smi[wid][e][lane]    = f[s*64+lane];
                smi[wid][e][64+lane] = f[d*64+lane];
                if(lane==0){ float t=w[ei]; smi[wid][e][128]=t*t; }
            }
        }
        __syncthreads();
        // phase 1: h1 = silu(mi @ W1 + b1)
        float h[EB];
        #pragma unroll
        for(int e=0;e<EB;++e) h[e]=sb1[lane];
        for(int k=0;k<128;k+=4){
            float w0=sW1[(k+0)*64+lane];
            float w1=sW1[(k+1)*64+lane];
            float w2=sW1[(k+2)*64+lane];
            float w3=sW1[(k+3)*64+lane];
            #pragma unroll
            for(int e=0;e<EB;++e){
                float4 m4=*(const float4*)&smi[wid][e][k];
                h[e] += m4.x*w0 + m4.y*w1 + m4.z*w2 + m4.w*w3;
            }
        }
        {
            float w128=sW1[128*64+lane];
            #pragma unroll
            for(int e=0;e<EB;++e) h[e] += smi[wid][e][128]*w128;
        }
        #pragma unroll
        for(int e=0;e<EB;++e) sh1[wid][e][lane]=silu_f(h[e]);
        __syncthreads();
        // phase 2: m = silu(silu(h1 @ W2 + b2)); atomic scatter
        float h2[EB];
        #pragma unroll
        for(int e=0;e<EB;++e) h2[e]=sb2[lane];
        for(int k=0;k<64;k+=4){
            float w0=sW2[(k+0)*64+lane];
            float w1=sW2[(k+1)*64+lane];
            float w2=sW2[(k+2)*64+lane];
            float w3=sW2[(k+3)*64+lane];
            #pragma unroll
            for(int e=0;e<EB;++e){
                float4 m4=*(const float4*)&sh1[wid][e][k];
                h2[e] += m4.x*w0 + m4.y*w1 + m4.z*w2 + m4.w*w3;
            }
        }
        #pragma unroll
        for(int e=0;e<EB;++e){
            if(dsts[e]>=0){
                float m = silu_f(silu_f(h2[e]));
                atomicAdd(&msum[dsts[e]*64+lane], m);
            }
        }
        __syncthreads();
    }
}

// out = (silu((A [+F]) @ W1 + b1) @ W2 + b2) [+F]; one wave per node
__global__ __launch_bounds__(256) void node_mlp2(const float* __restrict__ A, const float* __restrict__ F,
        const float* __restrict__ W1g, const float* __restrict__ b1g,
        const float* __restrict__ W2g, const float* __restrict__ b2g,
        float* __restrict__ out, int N){
    __shared__ __align__(16) float sW1[4096];
    __shared__ __align__(16) float sW2[4096];
    __shared__ float sb1[64], sb2[64];
    __shared__ __align__(16) float sin_[4][64];
    __shared__ __align__(16) float sh1[4][64];
    int tid=threadIdx.x, wid=tid>>6, lane=tid&63;
    for(int i=tid;i<4096;i+=256){ sW1[i]=W1g[i]; sW2[i]=W2g[i]; }
    if(tid<64){ sb1[tid]=b1g[tid]; sb2[tid]=b2g[tid]; }
    __syncthreads();
    int gw=gridDim.x*4;
    int n0=blockIdx.x*4+wid;
    int niter=(N+gw-1)/gw;
    for(int it=0;it<niter;++it){
        int n=n0+it*gw; bool act=n<N;
        float fo=0.0f;
        if(act){
            float in=A[n*64+lane];
            if(F){ fo=F[n*64+lane]; in+=fo; }
            sin_[wid][lane]=in;
        }
        __syncthreads();
        if(act){
            float h=sb1[lane];
            #pragma unroll
            for(int k=0;k<64;k+=4){
                float4 m4=*(const float4*)&sin_[wid][k];
                h += m4.x*sW1[k*64+lane]+m4.y*sW1[(k+1)*64+lane]
                   + m4.z*sW1[(k+2)*64+lane]+m4.w*sW1[(k+3)*64+lane];
            }
            sh1[wid][lane]=silu_f(h);
        }
        __syncthreads();
        if(act){
            float h=sb2[lane];
            #pragma unroll
            for(int k=0;k<64;k+=4){
                float4 m4=*(const float4*)&sh1[wid][k];
                h += m4.x*sW2[k*64+lane]+m4.y*sW2[(k+1)*64+lane]
                   + m4.z*sW2[(k+2)*64+lane]+m4.w*sW2[(k+3)*64+lane];
            }
            out[n*64+lane]=h+fo;
        }
        __syncthreads();
    }
}

// segment sum/max/count by graph id (atomics), one wave per node
__global__ __launch_bounds__(256) void seg_reduce(const float* __restrict__ f2, const int* __restrict__ gid,
        float* __restrict__ gsum, unsigned* __restrict__ gmaxu, float* __restrict__ cnt, int N){
    int tid=threadIdx.x, wid=tid>>6, lane=tid&63;
    int gw=gridDim.x*4;
    for(int n=blockIdx.x*4+wid; n<N; n+=gw){
        int g=gid[n];
        float v=f2[n*64+lane];
        atomicAdd(&gsum[g*64+lane], v);
        atomicMax(&gmaxu[g*64+lane], fenc(v));
        if(lane==0) atomicAdd(&cnt[g], 1.0f);
    }
}

// readout: r=[sum,mean,max] (192) -> silu(r@W1+b1) -> @W2 + b2 ; one wave per graph
__global__ __launch_bounds__(256) void readout_k(const float* __restrict__ gsum, const unsigned* __restrict__ gmaxu,
        const float* __restrict__ cnt,
        const float* __restrict__ W1, const float* __restrict__ b1,
        const float* __restrict__ W2, const float* __restrict__ b2,
        float* __restrict__ out, int G){
    __shared__ __align__(16) float sr[4][192];
    int tid=threadIdx.x, wid=tid>>6, lane=tid&63;
    int g=blockIdx.x*4+wid;
    if(g<G){
        float s_=gsum[g*64+lane];
        float c=cnt[g];
        float mean=s_/fmaxf(c,1.0f);
        float mx=fdec(gmaxu[g*64+lane]);
        sr[wid][lane]=s_; sr[wid][64+lane]=mean; sr[wid][128+lane]=mx;
    }
    __syncthreads();
    if(g<G){
        float h=b1[lane];
        for(int k=0;k<192;k+=4){
            float4 r4=*(const float4*)&sr[wid][k];
            h += r4.x*W1[(k+0)*64+lane] + r4.y*W1[(k+1)*64+lane]
               + r4.z*W1[(k+2)*64+lane] + r4.w*W1[(k+3)*64+lane];
        }
        h=silu_f(h);
        float p=h*W2[lane];
        #pragma unroll
        for(int off=32;off>0;off>>=1) p += __shfl_down(p, off, 64);
        if(lane==0) out[g]=p+b2[0];
    }
}

extern "C" void kernel_launch(void* const* d_in, const int* in_sizes, int n_in,
                              void* d_out, int out_size, void* d_ws, size_t ws_size,
                              hipStream_t stream){
    const float* x     = (const float*)d_in[0];
    const float* w     = (const float*)d_in[1];
    const int*   src   = (const int*)d_in[2];
    const int*   dst   = (const int*)d_in[3];
    const int*   gid   = (const int*)d_in[4];
    const float* W_in  = (const float*)d_in[5];
    const float* b_in  = (const float*)d_in[6];
    const float* msgW1 = (const float*)d_in[7];
    const float* msgb1 = (const float*)d_in[8];
    const float* msgW2 = (const float*)d_in[9];
    const float* msgb2 = (const float*)d_in[10];
    const float* updW1 = (const float*)d_in[11];
    const float* updb1 = (const float*)d_in[12];
    const float* updW2 = (const float*)d_in[13];
    const float* updb2 = (const float*)d_in[14];
    const float* outW1 = (const float*)d_in[15];
    const float* outb1 = (const float*)d_in[16];
    const float* outW2 = (const float*)d_in[17];
    const float* outb2 = (const float*)d_in[18];
    const float* roW1  = (const float*)d_in[19];
    const float* rob1  = (const float*)d_in[20];
    const float* roW2  = (const float*)d_in[21];
    const float* rob2  = (const float*)d_in[22];

    float* f    = (float*)d_ws;                   // N*64
    float* msum = f + (size_t)NN*64;              // N*64 (reused as f2 after layers)
    float* f2   = msum;
    float* gsum = msum + (size_t)NN*64;           // G*64
    unsigned* gmaxu = (unsigned*)(gsum + GG*64);  // G*64
    float* cnt  = (float*)(gmaxu + GG*64);        // G

    input_mlp<<<dim3(1024),dim3(256),0,stream>>>(x, W_in, b_in, f, NN);
    for(int l=0;l<LL;++l){
        hipMemsetAsync(msum, 0, (size_t)NN*64*sizeof(float), stream);
        edge_msg<<<dim3(512),dim3(256),0,stream>>>(f, src, dst, w,
            msgW1 + (size_t)l*129*64, msgb1 + l*64,
            msgW2 + (size_t)l*64*64,  msgb2 + l*64, msum, EE);
        node_mlp2<<<dim3(1024),dim3(256),0,stream>>>(msum, f,
            updW1 + (size_t)l*64*64, updb1 + l*64,
            updW2 + (size_t)l*64*64, updb2 + l*64, f, NN);
    }
    node_mlp2<<<dim3(1024),dim3(256),0,stream>>>(f, nullptr, outW1, outb1, outW2, outb2, f2, NN);
    hipMemsetAsync(gsum, 0, (size_t)(GG*64*2 + GG)*sizeof(float), stream);
    seg_reduce<<<dim3(512),dim3(256),0,stream>>>(f2, gid, gsum, gmaxu, cnt, NN);
    readout_k<<<dim3(32),dim3(256),0,stream>>>(gsum, gmaxu, cnt, roW1, rob1, roW2, rob2, (float*)d_out, GG);
}

// Round 2
// 1273.155 us; speedup vs baseline: 6.0954x; 6.0954x over previous
//
#include <hip/hip_runtime.h>

#define NN 50000
#define EE 800000
#define GG 128
#define LL 4

typedef __bf16 bf16x8 __attribute__((ext_vector_type(8)));
typedef float  f32x4  __attribute__((ext_vector_type(4)));

__device__ __forceinline__ float silu_f(float x){
    return x / (1.0f + __expf(-x));
}
__device__ __forceinline__ unsigned fenc(float v){
    unsigned u = __float_as_uint(v);
    return (u & 0x80000000u) ? ~u : (u | 0x80000000u);
}
__device__ __forceinline__ float fdec(unsigned u){
    return (u & 0x80000000u) ? __uint_as_float(u & 0x7fffffffu) : __uint_as_float(~u);
}

__global__ __launch_bounds__(256) void input_mlp(const float* __restrict__ x,
        const float* __restrict__ Wg, const float* __restrict__ bg,
        float* __restrict__ f, __bf16* __restrict__ f16, int N){
    __shared__ __align__(16) float sW[64*64];
    __shared__ float sb[64];
    __shared__ __align__(16) float srow[4][64];
    int tid=threadIdx.x, wid=tid>>6, lane=tid&63;
    for(int i=tid;i<4096;i+=256) sW[i]=Wg[i];
    if(tid<64) sb[tid]=bg[tid];
    __syncthreads();
    int gw=gridDim.x*4;
    int n0=blockIdx.x*4+wid;
    int niter=(N+gw-1)/gw;
    for(int it=0;it<niter;++it){
        int n=n0+it*gw; bool act = n<N;
        if(act) srow[wid][lane]=x[n*64+lane];
        __syncthreads();
        if(act){
            float h=sb[lane];
            #pragma unroll
            for(int k=0;k<64;k+=4){
                float4 m4=*(const float4*)&srow[wid][k];
                h += m4.x*sW[k*64+lane] + m4.y*sW[(k+1)*64+lane]
                   + m4.z*sW[(k+2)*64+lane] + m4.w*sW[(k+3)*64+lane];
            }
            float o=silu_f(h);
            f[n*64+lane]=o; f16[n*64+lane]=(__bf16)o;
        }
        __syncthreads();
    }
}

__global__ void hist_k(const int* __restrict__ dst, int* __restrict__ deg, int E){
    int e=blockIdx.x*blockDim.x+threadIdx.x;
    if(e<E) atomicAdd(&deg[dst[e]],1);
}
__global__ __launch_bounds__(1024) void scan_k(const int* __restrict__ deg, int* __restrict__ cursor, int N){
    __shared__ int part[1024];
    int tid=threadIdx.x;
    const int CH=(NN+1023)/1024;
    int i0=tid*CH;
    int s=0;
    for(int i=0;i<CH;++i){ int idx=i0+i; if(idx<N) s+=deg[idx]; }
    part[tid]=s; __syncthreads();
    for(int off=1; off<1024; off<<=1){
        int v=part[tid]; int a=(tid>=off)?part[tid-off]:0;
        __syncthreads(); part[tid]=v+a; __syncthreads();
    }
    int run=(tid>0)?part[tid-1]:0;
    for(int i=0;i<CH;++i){ int idx=i0+i; if(idx<N){ cursor[idx]=run; run+=deg[idx]; } }
}
__global__ void fill_k(const int* __restrict__ dst, int* __restrict__ cursor,
                       int* __restrict__ perm, int E){
    int e=blockIdx.x*blockDim.x+threadIdx.x;
    if(e<E){ int r=atomicAdd(&cursor[dst[e]],1); perm[r]=e; }
}

// edge message MLP via bf16 MFMA over 16-slot tiles of dst-sorted edges.
// A-frag: A[m=lane&15][k=(lane>>4)*8+j]; C/D: col=lane&15, row=(lane>>4)*4+reg.
__global__ __launch_bounds__(256) void edge_mfma(
        const __bf16* __restrict__ f16,
        const float* __restrict__ w, const int* __restrict__ src, const int* __restrict__ dst,
        const int* __restrict__ perm,
        const float* __restrict__ W1, const float* __restrict__ b1,
        const float* __restrict__ W2, const float* __restrict__ b2,
        float* __restrict__ msum, int E){
    int tid=threadIdx.x, wid=tid>>6, lane=tid&63;
    int q=lane>>4, nn=lane&15;

    bf16x8 B1f[4][4];
    #pragma unroll
    for(int s=0;s<4;++s)
        #pragma unroll
        for(int ng=0;ng<4;++ng){
            bf16x8 t;
            #pragma unroll
            for(int j=0;j<8;++j) t[j]=(__bf16)W1[(32*s+8*q+j)*64 + 16*ng + nn];
            B1f[s][ng]=t;
        }
    bf16x8 B2f[2][4];
    #pragma unroll
    for(int s=0;s<2;++s)
        #pragma unroll
        for(int ng=0;ng<4;++ng){
            bf16x8 t;
            #pragma unroll
            for(int j=0;j<8;++j) t[j]=(__bf16)W2[(32*s+8*q+j)*64 + 16*ng + nn];
            B2f[s][ng]=t;
        }
    float w128[4], bias1[4], bias2[4];
    #pragma unroll
    for(int ng=0;ng<4;++ng){
        w128[ng]=W1[128*64 + 16*ng + nn];
        bias1[ng]=b1[16*ng+nn];
        bias2[ng]=b2[16*ng+nn];
    }

    __shared__ __align__(16) __bf16 sh1[4][16][72];
    __shared__ float sm[4][16][65];

    int ntiles=(E+15)/16;
    int gw=gridDim.x*4;
    for(int t=blockIdx.x*4+wid; t<ntiles; t+=gw){
        int slot=t*16+lane;
        int eid=0; int d_=-1; int s_=0; float w2v=0.f;
        if(lane<16 && slot<E){
            eid=perm[slot];
            s_=src[eid]; d_=dst[eid];
            float ww=w[eid]; w2v=ww*ww;
        }
        int se=__shfl(s_, nn, 64);
        int de=__shfl(d_, nn, 64);
        if(de<0) de=0;  // safe address for invalid columns

        const __bf16* frs = f16 + (size_t)se*64;
        const __bf16* frd = f16 + (size_t)de*64;
        bf16x8 af0=*(const bf16x8*)(frs + 8*q);
        bf16x8 af1=*(const bf16x8*)(frs + 32 + 8*q);
        bf16x8 af2=*(const bf16x8*)(frd + 8*q);
        bf16x8 af3=*(const bf16x8*)(frd + 32 + 8*q);

        f32x4 acc[4];
        #pragma unroll
        for(int ng=0;ng<4;++ng){ f32x4 c; c[0]=bias1[ng]; c[1]=bias1[ng]; c[2]=bias1[ng]; c[3]=bias1[ng]; acc[ng]=c; }
        #pragma unroll
        for(int ng=0;ng<4;++ng){
            acc[ng]=__builtin_amdgcn_mfma_f32_16x16x32_bf16(af0,B1f[0][ng],acc[ng],0,0,0);
            acc[ng]=__builtin_amdgcn_mfma_f32_16x16x32_bf16(af1,B1f[1][ng],acc[ng],0,0,0);
            acc[ng]=__builtin_amdgcn_mfma_f32_16x16x32_bf16(af2,B1f[2][ng],acc[ng],0,0,0);
            acc[ng]=__builtin_amdgcn_mfma_f32_16x16x32_bf16(af3,B1f[3][ng],acc[ng],0,0,0);
        }
        #pragma unroll
        for(int r=0;r<4;++r){
            float w2r=__shfl(w2v, 4*q+r, 64);
            #pragma unroll
            for(int ng=0;ng<4;++ng) acc[ng][r]+=w2r*w128[ng];
        }
        #pragma unroll
        for(int ng=0;ng<4;++ng)
            #pragma unroll
            for(int r=0;r<4;++r)
                sh1[wid][4*q+r][16*ng+nn]=(__bf16)silu_f(acc[ng][r]);
        asm volatile("" ::: "memory");
        bf16x8 a20=*(const bf16x8*)&sh1[wid][nn][8*q];
        bf16x8 a21=*(const bf16x8*)&sh1[wid][nn][32+8*q];
        f32x4 acc2[4];
        #pragma unroll
        for(int ng=0;ng<4;++ng){ f32x4 c; c[0]=bias2[ng]; c[1]=bias2[ng]; c[2]=bias2[ng]; c[3]=bias2[ng]; acc2[ng]=c; }
        #pragma unroll
        for(int ng=0;ng<4;++ng){
            acc2[ng]=__builtin_amdgcn_mfma_f32_16x16x32_bf16(a20,B2f[0][ng],acc2[ng],0,0,0);
            acc2[ng]=__builtin_amdgcn_mfma_f32_16x16x32_bf16(a21,B2f[1][ng],acc2[ng],0,0,0);
        }
        #pragma unroll
        for(int ng=0;ng<4;++ng)
            #pragma unroll
            for(int r=0;r<4;++r)
                sm[wid][4*q+r][16*ng+nn]=silu_f(silu_f(acc2[ng][r]));
        asm volatile("" ::: "memory");
        float vsum=0.f; int cur=__shfl(d_, 0, 64);
        #pragma unroll
        for(int r=0;r<16;++r){
            int dr=__shfl(d_, r, 64);
            if(dr!=cur){
                if(cur>=0) atomicAdd(&msum[(size_t)cur*64+lane], vsum);
                vsum=0.f; cur=dr;
            }
            vsum+=sm[wid][r][lane];
        }
        if(cur>=0) atomicAdd(&msum[(size_t)cur*64+lane], vsum);
    }
}

__global__ __launch_bounds__(256) void node_mlp2(const float* __restrict__ A, const float* __restrict__ F,
        const float* __restrict__ W1g, const float* __restrict__ b1g,
        const float* __restrict__ W2g, const float* __restrict__ b2g,
        float* __restrict__ out, __bf16* __restrict__ out16, int N){
    __shared__ __align__(16) float sW1[4096];
    __shared__ __align__(16) float sW2[4096];
    __shared__ float sb1[64], sb2[64];
    __shared__ __align__(16) float sin_[4][64];
    __shared__ __align__(16) float sh1[4][64];
    int tid=threadIdx.x, wid=tid>>6, lane=tid&63;
    for(int i=tid;i<4096;i+=256){ sW1[i]=W1g[i]; sW2[i]=W2g[i]; }
    if(tid<64){ sb1[tid]=b1g[tid]; sb2[tid]=b2g[tid]; }
    __syncthreads();
    int gw=gridDim.x*4;
    int n0=blockIdx.x*4+wid;
    int niter=(N+gw-1)/gw;
    for(int it=0;it<niter;++it){
        int n=n0+it*gw; bool act=n<N;
        float fo=0.0f;
        if(act){
            float in=A[n*64+lane];
            if(F){ fo=F[n*64+lane]; in+=fo; }
            sin_[wid][lane]=in;
        }
        __syncthreads();
        if(act){
            float h=sb1[lane];
            #pragma unroll
            for(int k=0;k<64;k+=4){
                float4 m4=*(const float4*)&sin_[wid][k];
                h += m4.x*sW1[k*64+lane]+m4.y*sW1[(k+1)*64+lane]
                   + m4.z*sW1[(k+2)*64+lane]+m4.w*sW1[(k+3)*64+lane];
            }
            sh1[wid][lane]=silu_f(h);
        }
        __syncthreads();
        if(act){
            float h=sb2[lane];
            #pragma unroll
            for(int k=0;k<64;k+=4){
                float4 m4=*(const float4*)&sh1[wid][k];
                h += m4.x*sW2[k*64+lane]+m4.y*sW2[(k+1)*64+lane]
                   + m4.z*sW2[(k+2)*64+lane]+m4.w*sW2[(k+3)*64+lane];
            }
            float o=h+fo;
            out[n*64+lane]=o;
            if(out16) out16[n*64+lane]=(__bf16)o;
        }
        __syncthreads();
    }
}

__global__ __launch_bounds__(256) void seg_reduce(const float* __restrict__ f2, const int* __restrict__ gid,
        float* __restrict__ gsum, unsigned* __restrict__ gmaxu, float* __restrict__ cnt, int N){
    int tid=threadIdx.x, wid=tid>>6, lane=tid&63;
    int gw=gridDim.x*4;
    for(int n=blockIdx.x*4+wid; n<N; n+=gw){
        int g=gid[n];
        float v=f2[n*64+lane];
        atomicAdd(&gsum[g*64+lane], v);
        atomicMax(&gmaxu[g*64+lane], fenc(v));
        if(lane==0) atomicAdd(&cnt[g], 1.0f);
    }
}

__global__ __launch_bounds__(256) void readout_k(const float* __restrict__ gsum, const unsigned* __restrict__ gmaxu,
        const float* __restrict__ cnt,
        const float* __restrict__ W1, const float* __restrict__ b1,
        const float* __restrict__ W2, const float* __restrict__ b2,
        float* __restrict__ out, int G){
    __shared__ __align__(16) float sr[4][192];
    int tid=threadIdx.x, wid=tid>>6, lane=tid&63;
    int g=blockIdx.x*4+wid;
    if(g<G){
        float s_=gsum[g*64+lane];
        float c=cnt[g];
        float mean=s_/fmaxf(c,1.0f);
        float mx=fdec(gmaxu[g*64+lane]);
        sr[wid][lane]=s_; sr[wid][64+lane]=mean; sr[wid][128+lane]=mx;
    }
    __syncthreads();
    if(g<G){
        float h=b1[lane];
        for(int k=0;k<192;k+=4){
            float4 r4=*(const float4*)&sr[wid][k];
            h += r4.x*W1[(k+0)*64+lane] + r4.y*W1[(k+1)*64+lane]
               + r4.z*W1[(k+2)*64+lane] + r4.w*W1[(k+3)*64+lane];
        }
        h=silu_f(h);
        float p=h*W2[lane];
        #pragma unroll
        for(int off=32;off>0;off>>=1) p += __shfl_down(p, off, 64);
        if(lane==0) out[g]=p+b2[0];
    }
}

extern "C" void kernel_launch(void* const* d_in, const int* in_sizes, int n_in,
                              void* d_out, int out_size, void* d_ws, size_t ws_size,
                              hipStream_t stream){
    const float* x     = (const float*)d_in[0];
    const float* w     = (const float*)d_in[1];
    const int*   src   = (const int*)d_in[2];
    const int*   dst   = (const int*)d_in[3];
    const int*   gid   = (const int*)d_in[4];
    const float* W_in  = (const float*)d_in[5];
    const float* b_in  = (const float*)d_in[6];
    const float* msgW1 = (const float*)d_in[7];
    const float* msgb1 = (const float*)d_in[8];
    const float* msgW2 = (const float*)d_in[9];
    const float* msgb2 = (const float*)d_in[10];
    const float* updW1 = (const float*)d_in[11];
    const float* updb1 = (const float*)d_in[12];
    const float* updW2 = (const float*)d_in[13];
    const float* updb2 = (const float*)d_in[14];
    const float* outW1 = (const float*)d_in[15];
    const float* outb1 = (const float*)d_in[16];
    const float* outW2 = (const float*)d_in[17];
    const float* outb2 = (const float*)d_in[18];
    const float* roW1  = (const float*)d_in[19];
    const float* rob1  = (const float*)d_in[20];
    const float* roW2  = (const float*)d_in[21];
    const float* rob2  = (const float*)d_in[22];

    float*  f     = (float*)d_ws;                         // N*64 f32
    float*  msum  = f + (size_t)NN*64;                    // N*64 f32 (reused as f2)
    float*  f2    = msum;
    __bf16* f16   = (__bf16*)(msum + (size_t)NN*64);      // N*64 bf16
    int*    perm  = (int*)(f16 + (size_t)NN*64);          // E
    int*    deg   = perm + EE;                            // N (padded)
    int*    curs  = deg + 50048;                          // N (padded)
    float*  gsum  = (float*)(curs + 50048);               // G*64
    unsigned* gmaxu = (unsigned*)(gsum + GG*64);          // G*64
    float*  cnt   = (float*)(gmaxu + GG*64);              // G

    // CSR permutation: deg -> exclusive scan -> rank scatter
    hipMemsetAsync(deg, 0, 50048*sizeof(int), stream);
    hist_k<<<dim3((EE+255)/256),dim3(256),0,stream>>>(dst, deg, EE);
    scan_k<<<dim3(1),dim3(1024),0,stream>>>(deg, curs, NN);
    fill_k<<<dim3((EE+255)/256),dim3(256),0,stream>>>(dst, curs, perm, EE);

    input_mlp<<<dim3(1024),dim3(256),0,stream>>>(x, W_in, b_in, f, f16, NN);
    for(int l=0;l<LL;++l){
        hipMemsetAsync(msum, 0, (size_t)NN*64*sizeof(float), stream);
        edge_mfma<<<dim3(1024),dim3(256),0,stream>>>(f16, w, src, dst, perm,
            msgW1 + (size_t)l*129*64, msgb1 + l*64,
            msgW2 + (size_t)l*64*64,  msgb2 + l*64, msum, EE);
        node_mlp2<<<dim3(1024),dim3(256),0,stream>>>(msum, f,
            updW1 + (size_t)l*64*64, updb1 + l*64,
            updW2 + (size_t)l*64*64, updb2 + l*64, f, f16, NN);
    }
    node_mlp2<<<dim3(1024),dim3(256),0,stream>>>(f, nullptr, outW1, outb1, outW2, outb2, f2, nullptr, NN);
    hipMemsetAsync(gsum, 0, (size_t)(GG*64*2 + GG)*sizeof(float), stream);
    seg_reduce<<<dim3(512),dim3(256),0,stream>>>(f2, gid, gsum, gmaxu, cnt, NN);
    readout_k<<<dim3(32),dim3(256),0,stream>>>(gsum, gmaxu, cnt, roW1, rob1, roW2, rob2, (float*)d_out, GG);
}

// Round 3
// 910.196 us; speedup vs baseline: 8.5260x; 1.3988x over previous
//
#include <hip/hip_runtime.h>

#define NN 50000
#define EE 800000
#define GG 128
#define LL 4

typedef __bf16 bf16x8 __attribute__((ext_vector_type(8)));
typedef float  f32x4  __attribute__((ext_vector_type(4)));

__device__ __forceinline__ float silu_f(float x){
    return x / (1.0f + __expf(-x));
}
__device__ __forceinline__ unsigned fenc(float v){
    unsigned u = __float_as_uint(v);
    return (u & 0x80000000u) ? ~u : (u | 0x80000000u);
}
__device__ __forceinline__ float fdec(unsigned u){
    return (u & 0x80000000u) ? __uint_as_float(u & 0x7fffffffu) : __uint_as_float(~u);
}

__global__ __launch_bounds__(256) void input_mlp(const float* __restrict__ x,
        const float* __restrict__ Wg, const float* __restrict__ bg,
        float* __restrict__ f, __bf16* __restrict__ f16, int N){
    __shared__ __align__(16) float sW[64*64];
    __shared__ float sb[64];
    __shared__ __align__(16) float srow[4][64];
    int tid=threadIdx.x, wid=tid>>6, lane=tid&63;
    for(int i=tid;i<4096;i+=256) sW[i]=Wg[i];
    if(tid<64) sb[tid]=bg[tid];
    __syncthreads();
    int gw=gridDim.x*4;
    int n0=blockIdx.x*4+wid;
    int niter=(N+gw-1)/gw;
    for(int it=0;it<niter;++it){
        int n=n0+it*gw; bool act = n<N;
        if(act) srow[wid][lane]=x[n*64+lane];
        __syncthreads();
        if(act){
            float h=sb[lane];
            #pragma unroll
            for(int k=0;k<64;k+=4){
                float4 m4=*(const float4*)&srow[wid][k];
                h += m4.x*sW[k*64+lane] + m4.y*sW[(k+1)*64+lane]
                   + m4.z*sW[(k+2)*64+lane] + m4.w*sW[(k+3)*64+lane];
            }
            float o=silu_f(h);
            f[n*64+lane]=o; f16[n*64+lane]=(__bf16)o;
        }
        __syncthreads();
    }
}

__global__ void hist_k(const int* __restrict__ dst, int* __restrict__ deg, int E){
    int e=blockIdx.x*blockDim.x+threadIdx.x;
    if(e<E) atomicAdd(&deg[dst[e]],1);
}
__global__ __launch_bounds__(1024) void scan_k(const int* __restrict__ deg, int* __restrict__ cursor, int N){
    __shared__ int part[1024];
    int tid=threadIdx.x;
    const int CH=(NN+1023)/1024;
    int i0=tid*CH;
    int s=0;
    for(int i=0;i<CH;++i){ int idx=i0+i; if(idx<N) s+=deg[idx]; }
    part[tid]=s; __syncthreads();
    for(int off=1; off<1024; off<<=1){
        int v=part[tid]; int a=(tid>=off)?part[tid-off]:0;
        __syncthreads(); part[tid]=v+a; __syncthreads();
    }
    int run=(tid>0)?part[tid-1]:0;
    for(int i=0;i<CH;++i){ int idx=i0+i; if(idx<N){ cursor[idx]=run; run+=deg[idx]; } }
}
__global__ void fill_k(const int* __restrict__ dst, int* __restrict__ cursor,
                       int* __restrict__ perm, int E){
    int e=blockIdx.x*blockDim.x+threadIdx.x;
    if(e<E){ int r=atomicAdd(&cursor[dst[e]],1); perm[r]=e; }
}

// edge message MLP via bf16 MFMA over 32-slot tiles of dst-sorted edges.
// A-frag: A[m=lane&15][k=(lane>>4)*8+j]; C/D: col=lane&15, row=(lane>>4)*4+reg.
__global__ __launch_bounds__(256) void edge_mfma(
        const __bf16* __restrict__ f16,
        const float* __restrict__ w, const int* __restrict__ src, const int* __restrict__ dst,
        const int* __restrict__ perm,
        const float* __restrict__ W1, const float* __restrict__ b1,
        const float* __restrict__ W2, const float* __restrict__ b2,
        float* __restrict__ msum, int E){
    int tid=threadIdx.x, wid=tid>>6, lane=tid&63;
    int q=lane>>4, nn=lane&15;

    bf16x8 B1f[4][4];
    #pragma unroll
    for(int s=0;s<4;++s)
        #pragma unroll
        for(int ng=0;ng<4;++ng){
            bf16x8 t;
            #pragma unroll
            for(int j=0;j<8;++j) t[j]=(__bf16)W1[(32*s+8*q+j)*64 + 16*ng + nn];
            B1f[s][ng]=t;
        }
    bf16x8 B2f[2][4];
    #pragma unroll
    for(int s=0;s<2;++s)
        #pragma unroll
        for(int ng=0;ng<4;++ng){
            bf16x8 t;
            #pragma unroll
            for(int j=0;j<8;++j) t[j]=(__bf16)W2[(32*s+8*q+j)*64 + 16*ng + nn];
            B2f[s][ng]=t;
        }
    float w128[4], bias1[4], bias2[4];
    #pragma unroll
    for(int ng=0;ng<4;++ng){
        w128[ng]=W1[128*64 + 16*ng + nn];
        bias1[ng]=b1[16*ng+nn];
        bias2[ng]=b2[16*ng+nn];
    }

    __shared__ __align__(16) __bf16 sh1[4][32][72];
    __shared__ float sm[4][32][65];

    int ntiles=(E+31)/32;
    int gw=gridDim.x*4;
    for(int t=blockIdx.x*4+wid; t<ntiles; t+=gw){
        int slot=t*32+lane;
        int d_=-1; int s_=0; float w2v=0.f;
        if(lane<32 && slot<E){
            int eid=perm[slot];
            s_=src[eid]; d_=dst[eid];
            float ww=w[eid]; w2v=ww*ww;
        }
        // GEMM1 + silu for two 16-edge half-tiles
        #pragma unroll
        for(int h=0;h<2;++h){
            int se=__shfl(s_, 16*h+nn, 64);
            int de=__shfl(d_, 16*h+nn, 64);
            if(de<0) de=0;
            const __bf16* frs = f16 + (size_t)se*64;
            const __bf16* frd = f16 + (size_t)de*64;
            bf16x8 af0=*(const bf16x8*)(frs + 8*q);
            bf16x8 af1=*(const bf16x8*)(frs + 32 + 8*q);
            bf16x8 af2=*(const bf16x8*)(frd + 8*q);
            bf16x8 af3=*(const bf16x8*)(frd + 32 + 8*q);

            f32x4 acc[4];
            #pragma unroll
            for(int ng=0;ng<4;++ng){ f32x4 c; c[0]=bias1[ng]; c[1]=bias1[ng]; c[2]=bias1[ng]; c[3]=bias1[ng]; acc[ng]=c; }
            #pragma unroll
            for(int ng=0;ng<4;++ng){
                acc[ng]=__builtin_amdgcn_mfma_f32_16x16x32_bf16(af0,B1f[0][ng],acc[ng],0,0,0);
                acc[ng]=__builtin_amdgcn_mfma_f32_16x16x32_bf16(af1,B1f[1][ng],acc[ng],0,0,0);
                acc[ng]=__builtin_amdgcn_mfma_f32_16x16x32_bf16(af2,B1f[2][ng],acc[ng],0,0,0);
                acc[ng]=__builtin_amdgcn_mfma_f32_16x16x32_bf16(af3,B1f[3][ng],acc[ng],0,0,0);
            }
            #pragma unroll
            for(int r=0;r<4;++r){
                float w2r=__shfl(w2v, 16*h+4*q+r, 64);
                #pragma unroll
                for(int ng=0;ng<4;++ng) acc[ng][r]+=w2r*w128[ng];
            }
            #pragma unroll
            for(int ng=0;ng<4;++ng)
                #pragma unroll
                for(int r=0;r<4;++r)
                    sh1[wid][16*h+4*q+r][16*ng+nn]=(__bf16)silu_f(acc[ng][r]);
        }
        asm volatile("" ::: "memory");
        // GEMM2 + gate for both half-tiles
        #pragma unroll
        for(int h=0;h<2;++h){
            bf16x8 a20=*(const bf16x8*)&sh1[wid][16*h+nn][8*q];
            bf16x8 a21=*(const bf16x8*)&sh1[wid][16*h+nn][32+8*q];
            f32x4 acc2[4];
            #pragma unroll
            for(int ng=0;ng<4;++ng){ f32x4 c; c[0]=bias2[ng]; c[1]=bias2[ng]; c[2]=bias2[ng]; c[3]=bias2[ng]; acc2[ng]=c; }
            #pragma unroll
            for(int ng=0;ng<4;++ng){
                acc2[ng]=__builtin_amdgcn_mfma_f32_16x16x32_bf16(a20,B2f[0][ng],acc2[ng],0,0,0);
                acc2[ng]=__builtin_amdgcn_mfma_f32_16x16x32_bf16(a21,B2f[1][ng],acc2[ng],0,0,0);
            }
            #pragma unroll
            for(int ng=0;ng<4;++ng)
                #pragma unroll
                for(int r=0;r<4;++r)
                    sm[wid][16*h+4*q+r][16*ng+nn]=silu_f(silu_f(acc2[ng][r]));
        }
        asm volatile("" ::: "memory");
        // segmented scatter over the 32 dst-sorted rows
        float vsum=0.f; int cur=__shfl(d_, 0, 64);
        #pragma unroll
        for(int r=0;r<32;++r){
            int dr=__shfl(d_, r, 64);
            if(dr!=cur){
                if(cur>=0) atomicAdd(&msum[(size_t)cur*64+lane], vsum);
                vsum=0.f; cur=dr;
            }
            vsum+=sm[wid][r][lane];
        }
        if(cur>=0) atomicAdd(&msum[(size_t)cur*64+lane], vsum);
    }
}

// node 2-layer MLP via MFMA: out = silu((A[+F])@W1+b1)@W2+b2 [+F]
__global__ __launch_bounds__(256) void node_mfma(const float* __restrict__ A, const float* __restrict__ F,
        const float* __restrict__ W1, const float* __restrict__ b1,
        const float* __restrict__ W2, const float* __restrict__ b2,
        float* __restrict__ out, __bf16* __restrict__ out16, int N){
    int tid=threadIdx.x, wid=tid>>6, lane=tid&63;
    int q=lane>>4, nn=lane&15;

    bf16x8 B1f[2][4], B2f[2][4];
    #pragma unroll
    for(int s=0;s<2;++s)
        #pragma unroll
        for(int ng=0;ng<4;++ng){
            bf16x8 t1, t2;
            #pragma unroll
            for(int j=0;j<8;++j){
                t1[j]=(__bf16)W1[(32*s+8*q+j)*64 + 16*ng + nn];
                t2[j]=(__bf16)W2[(32*s+8*q+j)*64 + 16*ng + nn];
            }
            B1f[s][ng]=t1; B2f[s][ng]=t2;
        }
    float bias1[4], bias2[4];
    #pragma unroll
    for(int ng=0;ng<4;++ng){ bias1[ng]=b1[16*ng+nn]; bias2[ng]=b2[16*ng+nn]; }

    __shared__ __align__(16) __bf16 sh1[4][16][72];
    __shared__ __align__(16) float sF[4][16][68];
    bool hasF = (F != nullptr);

    int ntiles=(N+15)/16;
    int gw=gridDim.x*4;
    for(int t=blockIdx.x*4+wid; t<ntiles; t+=gw){
        int m=t*16+nn;                 // this lane's A-row (node)
        int mc=(m<N)?m:(N-1);
        // load 8 floats at k=8q.. and 8 at k=32+8q..
        float4 a0=*(const float4*)&A[(size_t)mc*64 + 8*q];
        float4 a1=*(const float4*)&A[(size_t)mc*64 + 8*q + 4];
        float4 a2=*(const float4*)&A[(size_t)mc*64 + 32 + 8*q];
        float4 a3=*(const float4*)&A[(size_t)mc*64 + 32 + 8*q + 4];
        if(hasF){
            float4 f0=*(const float4*)&F[(size_t)mc*64 + 8*q];
            float4 f1=*(const float4*)&F[(size_t)mc*64 + 8*q + 4];
            float4 f2_=*(const float4*)&F[(size_t)mc*64 + 32 + 8*q];
            float4 f3=*(const float4*)&F[(size_t)mc*64 + 32 + 8*q + 4];
            a0.x+=f0.x; a0.y+=f0.y; a0.z+=f0.z; a0.w+=f0.w;
            a1.x+=f1.x; a1.y+=f1.y; a1.z+=f1.z; a1.w+=f1.w;
            a2.x+=f2_.x; a2.y+=f2_.y; a2.z+=f2_.z; a2.w+=f2_.w;
            a3.x+=f3.x; a3.y+=f3.y; a3.z+=f3.z; a3.w+=f3.w;
            *(float4*)&sF[wid][nn][8*q]   = f0;
            *(float4*)&sF[wid][nn][8*q+4] = f1;
            *(float4*)&sF[wid][nn][32+8*q]   = f2_;
            *(float4*)&sF[wid][nn][32+8*q+4] = f3;
        }
        bf16x8 af0, af1;
        af0[0]=(__bf16)a0.x; af0[1]=(__bf16)a0.y; af0[2]=(__bf16)a0.z; af0[3]=(__bf16)a0.w;
        af0[4]=(__bf16)a1.x; af0[5]=(__bf16)a1.y; af0[6]=(__bf16)a1.z; af0[7]=(__bf16)a1.w;
        af1[0]=(__bf16)a2.x; af1[1]=(__bf16)a2.y; af1[2]=(__bf16)a2.z; af1[3]=(__bf16)a2.w;
        af1[4]=(__bf16)a3.x; af1[5]=(__bf16)a3.y; af1[6]=(__bf16)a3.z; af1[7]=(__bf16)a3.w;

        f32x4 acc[4];
        #pragma unroll
        for(int ng=0;ng<4;++ng){ f32x4 c; c[0]=bias1[ng]; c[1]=bias1[ng]; c[2]=bias1[ng]; c[3]=bias1[ng]; acc[ng]=c; }
        #pragma unroll
        for(int ng=0;ng<4;++ng){
            acc[ng]=__builtin_amdgcn_mfma_f32_16x16x32_bf16(af0,B1f[0][ng],acc[ng],0,0,0);
            acc[ng]=__builtin_amdgcn_mfma_f32_16x16x32_bf16(af1,B1f[1][ng],acc[ng],0,0,0);
        }
        #pragma unroll
        for(int ng=0;ng<4;++ng)
            #pragma unroll
            for(int r=0;r<4;++r)
                sh1[wid][4*q+r][16*ng+nn]=(__bf16)silu_f(acc[ng][r]);
        asm volatile("" ::: "memory");
        bf16x8 a20=*(const bf16x8*)&sh1[wid][nn][8*q];
        bf16x8 a21=*(const bf16x8*)&sh1[wid][nn][32+8*q];
        f32x4 acc2[4];
        #pragma unroll
        for(int ng=0;ng<4;++ng){ f32x4 c; c[0]=bias2[ng]; c[1]=bias2[ng]; c[2]=bias2[ng]; c[3]=bias2[ng]; acc2[ng]=c; }
        #pragma unroll
        for(int ng=0;ng<4;++ng){
            acc2[ng]=__builtin_amdgcn_mfma_f32_16x16x32_bf16(a20,B2f[0][ng],acc2[ng],0,0,0);
            acc2[ng]=__builtin_amdgcn_mfma_f32_16x16x32_bf16(a21,B2f[1][ng],acc2[ng],0,0,0);
        }
        #pragma unroll
        for(int ng=0;ng<4;++ng)
            #pragma unroll
            for(int r=0;r<4;++r){
                int row=t*16+4*q+r;
                if(row<N){
                    float o=acc2[ng][r];
                    if(hasF) o += sF[wid][4*q+r][16*ng+nn];
                    out[(size_t)row*64 + 16*ng + nn]=o;
                    if(out16) out16[(size_t)row*64 + 16*ng + nn]=(__bf16)o;
                }
            }
        asm volatile("" ::: "memory");
    }
}

// segment reduce exploiting SORTED graph_id: contiguous node range per wave,
// register accumulation, atomic flush only at segment boundaries.
__global__ __launch_bounds__(256) void seg_reduce_sorted(const float* __restrict__ f2, const int* __restrict__ gid,
        float* __restrict__ gsum, unsigned* __restrict__ gmaxu, float* __restrict__ cnt, int N){
    int wgl=blockIdx.x*4 + (threadIdx.x>>6);
    int lane=threadIdx.x&63;
    int W=gridDim.x*4;
    int chunk=(N+W-1)/W;
    int n0=wgl*chunk;
    int n1=n0+chunk; if(n1>N) n1=N;
    if(n0>=n1) return;
    int cur=gid[n0];
    float s=0.f, mx=-__builtin_inff(), c=0.f;
    for(int n=n0;n<n1;++n){
        int g=gid[n];
        float v=f2[(size_t)n*64+lane];
        if(g!=cur){
            atomicAdd(&gsum[(size_t)cur*64+lane], s);
            atomicMax(&gmaxu[(size_t)cur*64+lane], fenc(mx));
            if(lane==0) atomicAdd(&cnt[cur], c);
            s=0.f; mx=-__builtin_inff(); c=0.f; cur=g;
        }
        s+=v; mx=fmaxf(mx,v); c+=1.f;
    }
    atomicAdd(&gsum[(size_t)cur*64+lane], s);
    atomicMax(&gmaxu[(size_t)cur*64+lane], fenc(mx));
    if(lane==0) atomicAdd(&cnt[cur], c);
}

__global__ __launch_bounds__(256) void readout_k(const float* __restrict__ gsum, const unsigned* __restrict__ gmaxu,
        const float* __restrict__ cnt,
        const float* __restrict__ W1, const float* __restrict__ b1,
        const float* __restrict__ W2, const float* __restrict__ b2,
        float* __restrict__ out, int G){
    __shared__ __align__(16) float sr[4][192];
    int tid=threadIdx.x, wid=tid>>6, lane=tid&63;
    int g=blockIdx.x*4+wid;
    if(g<G){
        float s_=gsum[g*64+lane];
        float c=cnt[g];
        float mean=s_/fmaxf(c,1.0f);
        float mx=fdec(gmaxu[g*64+lane]);
        sr[wid][lane]=s_; sr[wid][64+lane]=mean; sr[wid][128+lane]=mx;
    }
    __syncthreads();
    if(g<G){
        float h=b1[lane];
        for(int k=0;k<192;k+=4){
            float4 r4=*(const float4*)&sr[wid][k];
            h += r4.x*W1[(k+0)*64+lane] + r4.y*W1[(k+1)*64+lane]
               + r4.z*W1[(k+2)*64+lane] + r4.w*W1[(k+3)*64+lane];
        }
        h=silu_f(h);
        float p=h*W2[lane];
        #pragma unroll
        for(int off=32;off>0;off>>=1) p += __shfl_down(p, off, 64);
        if(lane==0) out[g]=p+b2[0];
    }
}

extern "C" void kernel_launch(void* const* d_in, const int* in_sizes, int n_in,
                              void* d_out, int out_size, void* d_ws, size_t ws_size,
                              hipStream_t stream){
    const float* x     = (const float*)d_in[0];
    const float* w     = (const float*)d_in[1];
    const int*   src   = (const int*)d_in[2];
    const int*   dst   = (const int*)d_in[3];
    const int*   gid   = (const int*)d_in[4];
    const float* W_in  = (const float*)d_in[5];
    const float* b_in  = (const float*)d_in[6];
    const float* msgW1 = (const float*)d_in[7];
    const float* msgb1 = (const float*)d_in[8];
    const float* msgW2 = (const float*)d_in[9];
    const float* msgb2 = (const float*)d_in[10];
    const float* updW1 = (const float*)d_in[11];
    const float* updb1 = (const float*)d_in[12];
    const float* updW2 = (const float*)d_in[13];
    const float* updb2 = (const float*)d_in[14];
    const float* outW1 = (const float*)d_in[15];
    const float* outb1 = (const float*)d_in[16];
    const float* outW2 = (const float*)d_in[17];
    const float* outb2 = (const float*)d_in[18];
    const float* roW1  = (const float*)d_in[19];
    const float* rob1  = (const float*)d_in[20];
    const float* roW2  = (const float*)d_in[21];
    const float* rob2  = (const float*)d_in[22];

    float*  f     = (float*)d_ws;                         // N*64 f32
    float*  msum  = f + (size_t)NN*64;                    // N*64 f32 (reused as f2)
    float*  f2    = msum;
    __bf16* f16   = (__bf16*)(msum + (size_t)NN*64);      // N*64 bf16
    int*    perm  = (int*)(f16 + (size_t)NN*64);          // E
    int*    deg   = perm + EE;                            // N (padded)
    int*    curs  = deg + 50048;                          // N (padded)
    float*  gsum  = (float*)(curs + 50048);               // G*64
    unsigned* gmaxu = (unsigned*)(gsum + GG*64);          // G*64
    float*  cnt   = (float*)(gmaxu + GG*64);              // G

    hipMemsetAsync(deg, 0, 50048*sizeof(int), stream);
    hist_k<<<dim3((EE+255)/256),dim3(256),0,stream>>>(dst, deg, EE);
    scan_k<<<dim3(1),dim3(1024),0,stream>>>(deg, curs, NN);
    fill_k<<<dim3((EE+255)/256),dim3(256),0,stream>>>(dst, curs, perm, EE);

    input_mlp<<<dim3(1024),dim3(256),0,stream>>>(x, W_in, b_in, f, f16, NN);
    for(int l=0;l<LL;++l){
        hipMemsetAsync(msum, 0, (size_t)NN*64*sizeof(float), stream);
        edge_mfma<<<dim3(1024),dim3(256),0,stream>>>(f16, w, src, dst, perm,
            msgW1 + (size_t)l*129*64, msgb1 + l*64,
            msgW2 + (size_t)l*64*64,  msgb2 + l*64, msum, EE);
        node_mfma<<<dim3(782),dim3(256),0,stream>>>(msum, f,
            updW1 + (size_t)l*64*64, updb1 + l*64,
            updW2 + (size_t)l*64*64, updb2 + l*64, f, f16, NN);
    }
    node_mfma<<<dim3(782),dim3(256),0,stream>>>(f, nullptr, outW1, outb1, outW2, outb2, f2, nullptr, NN);
    hipMemsetAsync(gsum, 0, (size_t)(GG*64*2 + GG)*sizeof(float), stream);
    seg_reduce_sorted<<<dim3(256),dim3(256),0,stream>>>(f2, gid, gsum, gmaxu, cnt, NN);
    readout_k<<<dim3(32),dim3(256),0,stream>>>(gsum, gmaxu, cnt, roW1, rob1, roW2, rob2, (float*)d_out, GG);
}

// Round 4
// 787.948 us; speedup vs baseline: 9.8488x; 1.1551x over previous
//
#include <hip/hip_runtime.h>

#define NN 50000
#define EE 800000
#define GG 128
#define LL 4

typedef __bf16 bf16x8 __attribute__((ext_vector_type(8)));
typedef float  f32x4  __attribute__((ext_vector_type(4)));

// fast silu: x * rcp(1 + 2^(-x*log2e)) — v_exp_f32 + v_rcp_f32, no IEEE divide
__device__ __forceinline__ float silu_f(float x){
    float t = __builtin_amdgcn_exp2f(-1.44269504f * x);
    return x * __builtin_amdgcn_rcpf(1.0f + t);
}
__device__ __forceinline__ unsigned fenc(float v){
    unsigned u = __float_as_uint(v);
    return (u & 0x80000000u) ? ~u : (u | 0x80000000u);
}
__device__ __forceinline__ float fdec(unsigned u){
    return (u & 0x80000000u) ? __uint_as_float(u & 0x7fffffffu) : __uint_as_float(~u);
}

__global__ __launch_bounds__(256) void input_mlp(const float* __restrict__ x,
        const float* __restrict__ Wg, const float* __restrict__ bg,
        float* __restrict__ f, __bf16* __restrict__ f16, int N){
    __shared__ __align__(16) float sW[64*64];
    __shared__ float sb[64];
    __shared__ __align__(16) float srow[4][64];
    int tid=threadIdx.x, wid=tid>>6, lane=tid&63;
    for(int i=tid;i<4096;i+=256) sW[i]=Wg[i];
    if(tid<64) sb[tid]=bg[tid];
    __syncthreads();
    int gw=gridDim.x*4;
    int n0=blockIdx.x*4+wid;
    int niter=(N+gw-1)/gw;
    for(int it=0;it<niter;++it){
        int n=n0+it*gw; bool act = n<N;
        if(act) srow[wid][lane]=x[n*64+lane];
        __syncthreads();
        if(act){
            float h=sb[lane];
            #pragma unroll
            for(int k=0;k<64;k+=4){
                float4 m4=*(const float4*)&srow[wid][k];
                h += m4.x*sW[k*64+lane] + m4.y*sW[(k+1)*64+lane]
                   + m4.z*sW[(k+2)*64+lane] + m4.w*sW[(k+3)*64+lane];
            }
            float o=silu_f(h);
            f[n*64+lane]=o; f16[n*64+lane]=(__bf16)o;
        }
        __syncthreads();
    }
}

__global__ void hist_k(const int* __restrict__ dst, int* __restrict__ deg, int E){
    int e=blockIdx.x*blockDim.x+threadIdx.x;
    if(e<E) atomicAdd(&deg[dst[e]],1);
}
__global__ __launch_bounds__(1024) void scan_k(const int* __restrict__ deg, int* __restrict__ cursor, int N){
    __shared__ int part[1024];
    int tid=threadIdx.x;
    const int CH=(NN+1023)/1024;
    int i0=tid*CH;
    int s=0;
    for(int i=0;i<CH;++i){ int idx=i0+i; if(idx<N) s+=deg[idx]; }
    part[tid]=s; __syncthreads();
    for(int off=1; off<1024; off<<=1){
        int v=part[tid]; int a=(tid>=off)?part[tid-off]:0;
        __syncthreads(); part[tid]=v+a; __syncthreads();
    }
    int run=(tid>0)?part[tid-1]:0;
    for(int i=0;i<CH;++i){ int idx=i0+i; if(idx<N){ cursor[idx]=run; run+=deg[idx]; } }
}
__global__ void fill_k(const int* __restrict__ dst, int* __restrict__ cursor,
                       int* __restrict__ perm, int E){
    int e=blockIdx.x*blockDim.x+threadIdx.x;
    if(e<E){ int r=atomicAdd(&cursor[dst[e]],1); perm[r]=e; }
}

// XY[n] = [ f@W1[0:64] | f@W1[64:128] ]  (N x 128, bf16). 16 nodes/tile, 8 ngroups, K=64.
__global__ __launch_bounds__(256) void xy_mfma(const __bf16* __restrict__ f16,
        const float* __restrict__ W1, __bf16* __restrict__ XY, int N){
    int tid=threadIdx.x, wid=tid>>6, lane=tid&63;
    int q=lane>>4, nn=lane&15;
    bf16x8 Bf[2][8];
    #pragma unroll
    for(int s=0;s<2;++s)
        #pragma unroll
        for(int ng=0;ng<8;++ng){
            bf16x8 t;
            #pragma unroll
            for(int j=0;j<8;++j){
                int k=32*s+8*q+j, c=16*ng+nn;
                float v = (c<64) ? W1[k*64+c] : W1[(64+k)*64 + (c-64)];
                t[j]=(__bf16)v;
            }
            Bf[s][ng]=t;
        }
    int ntiles=(N+15)/16;
    int gw=gridDim.x*4;
    for(int t=blockIdx.x*4+wid; t<ntiles; t+=gw){
        int row=t*16+nn; if(row>=N) row=N-1;
        bf16x8 a0=*(const bf16x8*)&f16[(size_t)row*64 + 8*q];
        bf16x8 a1=*(const bf16x8*)&f16[(size_t)row*64 + 32 + 8*q];
        #pragma unroll
        for(int ng=0;ng<8;++ng){
            f32x4 acc; acc[0]=0.f; acc[1]=0.f; acc[2]=0.f; acc[3]=0.f;
            acc=__builtin_amdgcn_mfma_f32_16x16x32_bf16(a0,Bf[0][ng],acc,0,0,0);
            acc=__builtin_amdgcn_mfma_f32_16x16x32_bf16(a1,Bf[1][ng],acc,0,0,0);
            #pragma unroll
            for(int r=0;r<4;++r){
                int orow=t*16+4*q+r;
                if(orow<N) XY[(size_t)orow*128 + 16*ng + nn]=(__bf16)acc[r];
            }
        }
    }
}

// edge kernel: h1 = silu(X[src]+Y[dst]+w^2*W1[128]+b1) built directly in A-frag regs,
// GEMM2 via MFMA, gated, segmented scatter over dst-sorted 32-slot tiles.
__global__ __launch_bounds__(256) void edge_mfma2(
        const __bf16* __restrict__ XY,
        const float* __restrict__ w, const int* __restrict__ src, const int* __restrict__ dst,
        const int* __restrict__ perm,
        const float* __restrict__ W1, const float* __restrict__ b1,
        const float* __restrict__ W2, const float* __restrict__ b2,
        float* __restrict__ msum, int E){
    int tid=threadIdx.x, wid=tid>>6, lane=tid&63;
    int q=lane>>4, nn=lane&15;

    bf16x8 B2f[2][4];
    #pragma unroll
    for(int s=0;s<2;++s)
        #pragma unroll
        for(int ng=0;ng<4;++ng){
            bf16x8 t;
            #pragma unroll
            for(int j=0;j<8;++j) t[j]=(__bf16)W2[(32*s+8*q+j)*64 + 16*ng + nn];
            B2f[s][ng]=t;
        }
    float w128lo[8], w128hi[8], b1lo[8], b1hi[8];
    #pragma unroll
    for(int j=0;j<8;++j){
        w128lo[j]=W1[128*64 + 8*q+j];
        w128hi[j]=W1[128*64 + 32+8*q+j];
        b1lo[j]=b1[8*q+j];
        b1hi[j]=b1[32+8*q+j];
    }
    float bias2[4];
    #pragma unroll
    for(int ng=0;ng<4;++ng) bias2[ng]=b2[16*ng+nn];

    __shared__ float sm[4][32][68];   // stride 68: conflict-free writes (272B rows)

    int ntiles=E/32;                  // E divisible by 32
    int gw=gridDim.x*4;
    for(int t=blockIdx.x*4+wid; t<ntiles; t+=gw){
        int slot=t*32+lane;
        int d_=-1, s_=0; float w2v=0.f;
        if(lane<32){
            int eid=perm[slot];
            s_=src[eid]; d_=dst[eid];
            float ww=w[eid]; w2v=ww*ww;
        }
        #pragma unroll
        for(int h=0;h<2;++h){
            int se=__shfl(s_, 16*h+nn, 64);
            int de=__shfl(d_, 16*h+nn, 64);
            float w2=__shfl(w2v, 16*h+nn, 64);
            const __bf16* xp = XY + (size_t)se*128;
            const __bf16* yp = XY + (size_t)de*128 + 64;
            bf16x8 xlo=*(const bf16x8*)(xp + 8*q);
            bf16x8 xhi=*(const bf16x8*)(xp + 32 + 8*q);
            bf16x8 ylo=*(const bf16x8*)(yp + 8*q);
            bf16x8 yhi=*(const bf16x8*)(yp + 32 + 8*q);
            bf16x8 a20, a21;
            #pragma unroll
            for(int j=0;j<8;++j){
                float hlo=(float)xlo[j] + (float)ylo[j] + w2*w128lo[j] + b1lo[j];
                float hhi=(float)xhi[j] + (float)yhi[j] + w2*w128hi[j] + b1hi[j];
                a20[j]=(__bf16)silu_f(hlo);
                a21[j]=(__bf16)silu_f(hhi);
            }
            f32x4 acc2[4];
            #pragma unroll
            for(int ng=0;ng<4;++ng){ f32x4 c; c[0]=bias2[ng]; c[1]=bias2[ng]; c[2]=bias2[ng]; c[3]=bias2[ng]; acc2[ng]=c; }
            #pragma unroll
            for(int ng=0;ng<4;++ng){
                acc2[ng]=__builtin_amdgcn_mfma_f32_16x16x32_bf16(a20,B2f[0][ng],acc2[ng],0,0,0);
                acc2[ng]=__builtin_amdgcn_mfma_f32_16x16x32_bf16(a21,B2f[1][ng],acc2[ng],0,0,0);
            }
            #pragma unroll
            for(int ng=0;ng<4;++ng)
                #pragma unroll
                for(int r=0;r<4;++r)
                    sm[wid][16*h+4*q+r][16*ng+nn]=silu_f(silu_f(acc2[ng][r]));
        }
        asm volatile("" ::: "memory");
        float vsum=0.f; int cur=__shfl(d_, 0, 64);
        #pragma unroll
        for(int r=0;r<32;++r){
            int dr=__shfl(d_, r, 64);
            if(dr!=cur){
                if(cur>=0) atomicAdd(&msum[(size_t)cur*64+lane], vsum);
                vsum=0.f; cur=dr;
            }
            vsum+=sm[wid][r][lane];
        }
        if(cur>=0) atomicAdd(&msum[(size_t)cur*64+lane], vsum);
        asm volatile("" ::: "memory");
    }
}

// node 2-layer MLP via MFMA: out = silu((A[+F])@W1+b1)@W2+b2 [+F]
__global__ __launch_bounds__(256) void node_mfma(const float* __restrict__ A, const float* __restrict__ F,
        const float* __restrict__ W1, const float* __restrict__ b1,
        const float* __restrict__ W2, const float* __restrict__ b2,
        float* __restrict__ out, __bf16* __restrict__ out16, int N){
    int tid=threadIdx.x, wid=tid>>6, lane=tid&63;
    int q=lane>>4, nn=lane&15;

    bf16x8 B1f[2][4], B2f[2][4];
    #pragma unroll
    for(int s=0;s<2;++s)
        #pragma unroll
        for(int ng=0;ng<4;++ng){
            bf16x8 t1, t2;
            #pragma unroll
            for(int j=0;j<8;++j){
                t1[j]=(__bf16)W1[(32*s+8*q+j)*64 + 16*ng + nn];
                t2[j]=(__bf16)W2[(32*s+8*q+j)*64 + 16*ng + nn];
            }
            B1f[s][ng]=t1; B2f[s][ng]=t2;
        }
    float bias1[4], bias2[4];
    #pragma unroll
    for(int ng=0;ng<4;++ng){ bias1[ng]=b1[16*ng+nn]; bias2[ng]=b2[16*ng+nn]; }

    __shared__ __align__(16) __bf16 sh1[4][16][72];
    __shared__ __align__(16) float sF[4][16][68];
    bool hasF = (F != nullptr);

    int ntiles=(N+15)/16;
    int gw=gridDim.x*4;
    for(int t=blockIdx.x*4+wid; t<ntiles; t+=gw){
        int m=t*16+nn;
        int mc=(m<N)?m:(N-1);
        float4 a0=*(const float4*)&A[(size_t)mc*64 + 8*q];
        float4 a1=*(const float4*)&A[(size_t)mc*64 + 8*q + 4];
        float4 a2=*(const float4*)&A[(size_t)mc*64 + 32 + 8*q];
        float4 a3=*(const float4*)&A[(size_t)mc*64 + 32 + 8*q + 4];
        if(hasF){
            float4 f0=*(const float4*)&F[(size_t)mc*64 + 8*q];
            float4 f1=*(const float4*)&F[(size_t)mc*64 + 8*q + 4];
            float4 f2_=*(const float4*)&F[(size_t)mc*64 + 32 + 8*q];
            float4 f3=*(const float4*)&F[(size_t)mc*64 + 32 + 8*q + 4];
            a0.x+=f0.x; a0.y+=f0.y; a0.z+=f0.z; a0.w+=f0.w;
            a1.x+=f1.x; a1.y+=f1.y; a1.z+=f1.z; a1.w+=f1.w;
            a2.x+=f2_.x; a2.y+=f2_.y; a2.z+=f2_.z; a2.w+=f2_.w;
            a3.x+=f3.x; a3.y+=f3.y; a3.z+=f3.z; a3.w+=f3.w;
            *(float4*)&sF[wid][nn][8*q]   = f0;
            *(float4*)&sF[wid][nn][8*q+4] = f1;
            *(float4*)&sF[wid][nn][32+8*q]   = f2_;
            *(float4*)&sF[wid][nn][32+8*q+4] = f3;
        }
        bf16x8 af0, af1;
        af0[0]=(__bf16)a0.x; af0[1]=(__bf16)a0.y; af0[2]=(__bf16)a0.z; af0[3]=(__bf16)a0.w;
        af0[4]=(__bf16)a1.x; af0[5]=(__bf16)a1.y; af0[6]=(__bf16)a1.z; af0[7]=(__bf16)a1.w;
        af1[0]=(__bf16)a2.x; af1[1]=(__bf16)a2.y; af1[2]=(__bf16)a2.z; af1[3]=(__bf16)a2.w;
        af1[4]=(__bf16)a3.x; af1[5]=(__bf16)a3.y; af1[6]=(__bf16)a3.z; af1[7]=(__bf16)a3.w;

        f32x4 acc[4];
        #pragma unroll
        for(int ng=0;ng<4;++ng){ f32x4 c; c[0]=bias1[ng]; c[1]=bias1[ng]; c[2]=bias1[ng]; c[3]=bias1[ng]; acc[ng]=c; }
        #pragma unroll
        for(int ng=0;ng<4;++ng){
            acc[ng]=__builtin_amdgcn_mfma_f32_16x16x32_bf16(af0,B1f[0][ng],acc[ng],0,0,0);
            acc[ng]=__builtin_amdgcn_mfma_f32_16x16x32_bf16(af1,B1f[1][ng],acc[ng],0,0,0);
        }
        #pragma unroll
        for(int ng=0;ng<4;++ng)
            #pragma unroll
            for(int r=0;r<4;++r)
                sh1[wid][4*q+r][16*ng+nn]=(__bf16)silu_f(acc[ng][r]);
        asm volatile("" ::: "memory");
        bf16x8 a20=*(const bf16x8*)&sh1[wid][nn][8*q];
        bf16x8 a21=*(const bf16x8*)&sh1[wid][nn][32+8*q];
        f32x4 acc2[4];
        #pragma unroll
        for(int ng=0;ng<4;++ng){ f32x4 c; c[0]=bias2[ng]; c[1]=bias2[ng]; c[2]=bias2[ng]; c[3]=bias2[ng]; acc2[ng]=c; }
        #pragma unroll
        for(int ng=0;ng<4;++ng){
            acc2[ng]=__builtin_amdgcn_mfma_f32_16x16x32_bf16(a20,B2f[0][ng],acc2[ng],0,0,0);
            acc2[ng]=__builtin_amdgcn_mfma_f32_16x16x32_bf16(a21,B2f[1][ng],acc2[ng],0,0,0);
        }
        #pragma unroll
        for(int ng=0;ng<4;++ng)
            #pragma unroll
            for(int r=0;r<4;++r){
                int row=t*16+4*q+r;
                if(row<N){
                    float o=acc2[ng][r];
                    if(hasF) o += sF[wid][4*q+r][16*ng+nn];
                    out[(size_t)row*64 + 16*ng + nn]=o;
                    if(out16) out16[(size_t)row*64 + 16*ng + nn]=(__bf16)o;
                }
            }
        asm volatile("" ::: "memory");
    }
}

__global__ __launch_bounds__(256) void seg_reduce_sorted(const float* __restrict__ f2, const int* __restrict__ gid,
        float* __restrict__ gsum, unsigned* __restrict__ gmaxu, float* __restrict__ cnt, int N){
    int wgl=blockIdx.x*4 + (threadIdx.x>>6);
    int lane=threadIdx.x&63;
    int W=gridDim.x*4;
    int chunk=(N+W-1)/W;
    int n0=wgl*chunk;
    int n1=n0+chunk; if(n1>N) n1=N;
    if(n0>=n1) return;
    int cur=gid[n0];
    float s=0.f, mx=-__builtin_inff(), c=0.f;
    for(int n=n0;n<n1;++n){
        int g=gid[n];
        float v=f2[(size_t)n*64+lane];
        if(g!=cur){
            atomicAdd(&gsum[(size_t)cur*64+lane], s);
            atomicMax(&gmaxu[(size_t)cur*64+lane], fenc(mx));
            if(lane==0) atomicAdd(&cnt[cur], c);
            s=0.f; mx=-__builtin_inff(); c=0.f; cur=g;
        }
        s+=v; mx=fmaxf(mx,v); c+=1.f;
    }
    atomicAdd(&gsum[(size_t)cur*64+lane], s);
    atomicMax(&gmaxu[(size_t)cur*64+lane], fenc(mx));
    if(lane==0) atomicAdd(&cnt[cur], c);
}

__global__ __launch_bounds__(256) void readout_k(const float* __restrict__ gsum, const unsigned* __restrict__ gmaxu,
        const float* __restrict__ cnt,
        const float* __restrict__ W1, const float* __restrict__ b1,
        const float* __restrict__ W2, const float* __restrict__ b2,
        float* __restrict__ out, int G){
    __shared__ __align__(16) float sr[4][192];
    int tid=threadIdx.x, wid=tid>>6, lane=tid&63;
    int g=blockIdx.x*4+wid;
    if(g<G){
        float s_=gsum[g*64+lane];
        float c=cnt[g];
        float mean=s_/fmaxf(c,1.0f);
        float mx=fdec(gmaxu[g*64+lane]);
        sr[wid][lane]=s_; sr[wid][64+lane]=mean; sr[wid][128+lane]=mx;
    }
    __syncthreads();
    if(g<G){
        float h=b1[lane];
        for(int k=0;k<192;k+=4){
            float4 r4=*(const float4*)&sr[wid][k];
            h += r4.x*W1[(k+0)*64+lane] + r4.y*W1[(k+1)*64+lane]
               + r4.z*W1[(k+2)*64+lane] + r4.w*W1[(k+3)*64+lane];
        }
        h=silu_f(h);
        float p=h*W2[lane];
        #pragma unroll
        for(int off=32;off>0;off>>=1) p += __shfl_down(p, off, 64);
        if(lane==0) out[g]=p+b2[0];
    }
}

extern "C" void kernel_launch(void* const* d_in, const int* in_sizes, int n_in,
                              void* d_out, int out_size, void* d_ws, size_t ws_size,
                              hipStream_t stream){
    const float* x     = (const float*)d_in[0];
    const float* w     = (const float*)d_in[1];
    const int*   src   = (const int*)d_in[2];
    const int*   dst   = (const int*)d_in[3];
    const int*   gid   = (const int*)d_in[4];
    const float* W_in  = (const float*)d_in[5];
    const float* b_in  = (const float*)d_in[6];
    const float* msgW1 = (const float*)d_in[7];
    const float* msgb1 = (const float*)d_in[8];
    const float* msgW2 = (const float*)d_in[9];
    const float* msgb2 = (const float*)d_in[10];
    const float* updW1 = (const float*)d_in[11];
    const float* updb1 = (const float*)d_in[12];
    const float* updW2 = (const float*)d_in[13];
    const float* updb2 = (const float*)d_in[14];
    const float* outW1 = (const float*)d_in[15];
    const float* outb1 = (const float*)d_in[16];
    const float* outW2 = (const float*)d_in[17];
    const float* outb2 = (const float*)d_in[18];
    const float* roW1  = (const float*)d_in[19];
    const float* rob1  = (const float*)d_in[20];
    const float* roW2  = (const float*)d_in[21];
    const float* rob2  = (const float*)d_in[22];

    float*  f     = (float*)d_ws;                         // N*64 f32
    float*  msum  = f + (size_t)NN*64;                    // N*64 f32 (reused as f2)
    float*  f2    = msum;
    __bf16* f16   = (__bf16*)(msum + (size_t)NN*64);      // N*64 bf16
    __bf16* XY    = f16 + (size_t)NN*64;                  // N*128 bf16
    int*    perm  = (int*)(XY + (size_t)NN*128);          // E
    int*    deg   = perm + EE;                            // N (padded)
    int*    curs  = deg + 50048;                          // N (padded)
    float*  gsum  = (float*)(curs + 50048);               // G*64
    unsigned* gmaxu = (unsigned*)(gsum + GG*64);          // G*64
    float*  cnt   = (float*)(gmaxu + GG*64);              // G

    hipMemsetAsync(deg, 0, 50048*sizeof(int), stream);
    hist_k<<<dim3((EE+255)/256),dim3(256),0,stream>>>(dst, deg, EE);
    scan_k<<<dim3(1),dim3(1024),0,stream>>>(deg, curs, NN);
    fill_k<<<dim3((EE+255)/256),dim3(256),0,stream>>>(dst, curs, perm, EE);

    input_mlp<<<dim3(1024),dim3(256),0,stream>>>(x, W_in, b_in, f, f16, NN);
    for(int l=0;l<LL;++l){
        xy_mfma<<<dim3(512),dim3(256),0,stream>>>(f16, msgW1 + (size_t)l*129*64, XY, NN);
        hipMemsetAsync(msum, 0, (size_t)NN*64*sizeof(float), stream);
        edge_mfma2<<<dim3(1024),dim3(256),0,stream>>>(XY, w, src, dst, perm,
            msgW1 + (size_t)l*129*64, msgb1 + l*64,
            msgW2 + (size_t)l*64*64,  msgb2 + l*64, msum, EE);
        node_mfma<<<dim3(782),dim3(256),0,stream>>>(msum, f,
            updW1 + (size_t)l*64*64, updb1 + l*64,
            updW2 + (size_t)l*64*64, updb2 + l*64, f, f16, NN);
    }
    node_mfma<<<dim3(782),dim3(256),0,stream>>>(f, nullptr, outW1, outb1, outW2, outb2, f2, nullptr, NN);
    hipMemsetAsync(gsum, 0, (size_t)(GG*64*2 + GG)*sizeof(float), stream);
    seg_reduce_sorted<<<dim3(256),dim3(256),0,stream>>>(f2, gid, gsum, gmaxu, cnt, NN);
    readout_k<<<dim3(32),dim3(256),0,stream>>>(gsum, gmaxu, cnt, roW1, rob1, roW2, rob2, (float*)d_out, GG);
}

// Round 5
// 710.461 us; speedup vs baseline: 10.9230x; 1.1091x over previous
//
#include <hip/hip_runtime.h>

#define NN 50000
#define EE 800000
#define GG 128
#define LL 4
#define SCAN_B 196   // ceil(50048/256)

typedef __bf16 bf16x8 __attribute__((ext_vector_type(8)));
typedef float  f32x4  __attribute__((ext_vector_type(4)));

// fast silu: x * rcp(1 + 2^(-x*log2e))
__device__ __forceinline__ float silu_f(float x){
    float t = __builtin_amdgcn_exp2f(-1.44269504f * x);
    return x * __builtin_amdgcn_rcpf(1.0f + t);
}
__device__ __forceinline__ unsigned fenc(float v){
    unsigned u = __float_as_uint(v);
    return (u & 0x80000000u) ? ~u : (u | 0x80000000u);
}
__device__ __forceinline__ float fdec(unsigned u){
    return (u & 0x80000000u) ? __uint_as_float(u & 0x7fffffffu) : __uint_as_float(~u);
}

__global__ __launch_bounds__(256) void input_mlp(const float* __restrict__ x,
        const float* __restrict__ Wg, const float* __restrict__ bg,
        float* __restrict__ f, __bf16* __restrict__ f16, int N){
    __shared__ __align__(16) float sW[64*64];
    __shared__ float sb[64];
    __shared__ __align__(16) float srow[4][64];
    int tid=threadIdx.x, wid=tid>>6, lane=tid&63;
    for(int i=tid;i<4096;i+=256) sW[i]=Wg[i];
    if(tid<64) sb[tid]=bg[tid];
    __syncthreads();
    int gw=gridDim.x*4;
    int n0=blockIdx.x*4+wid;
    int niter=(N+gw-1)/gw;
    for(int it=0;it<niter;++it){
        int n=n0+it*gw; bool act = n<N;
        if(act) srow[wid][lane]=x[n*64+lane];
        __syncthreads();
        if(act){
            float h=sb[lane];
            #pragma unroll
            for(int k=0;k<64;k+=4){
                float4 m4=*(const float4*)&srow[wid][k];
                h += m4.x*sW[k*64+lane] + m4.y*sW[(k+1)*64+lane]
                   + m4.z*sW[(k+2)*64+lane] + m4.w*sW[(k+3)*64+lane];
            }
            float o=silu_f(h);
            f[n*64+lane]=o; f16[n*64+lane]=(__bf16)o;
        }
        __syncthreads();
    }
}

__global__ void hist_k(const int* __restrict__ dst, int* __restrict__ deg, int E){
    int e=blockIdx.x*blockDim.x+threadIdx.x;
    if(e<E) atomicAdd(&deg[dst[e]],1);
}

// ---- 3-pass parallel exclusive scan of deg[0..N) -> curs[0..N) ----
__global__ __launch_bounds__(256) void scan1_k(const int* __restrict__ deg, int* __restrict__ curs,
        int* __restrict__ bsum, int N){
    __shared__ int sv[256];
    int tid=threadIdx.x;
    int idx=blockIdx.x*256+tid;
    int v=(idx<N)?deg[idx]:0;
    sv[tid]=v; __syncthreads();
    // inclusive scan in LDS
    #pragma unroll
    for(int off=1; off<256; off<<=1){
        int a=(tid>=off)?sv[tid-off]:0;
        __syncthreads(); sv[tid]+=a; __syncthreads();
    }
    if(idx<N) curs[idx]=sv[tid]-v;          // exclusive within block
    if(tid==255) bsum[blockIdx.x]=sv[255];  // block total
}
__global__ __launch_bounds__(256) void scan2_k(int* __restrict__ bsum, int B){
    __shared__ int sv[256];
    int tid=threadIdx.x;
    int v=(tid<B)?bsum[tid]:0;
    sv[tid]=v; __syncthreads();
    #pragma unroll
    for(int off=1; off<256; off<<=1){
        int a=(tid>=off)?sv[tid-off]:0;
        __syncthreads(); sv[tid]+=a; __syncthreads();
    }
    if(tid<B) bsum[tid]=sv[tid]-v;          // exclusive block offsets
}
__global__ __launch_bounds__(256) void scan3_k(int* __restrict__ curs, const int* __restrict__ bsum, int N){
    int idx=blockIdx.x*256+threadIdx.x;
    if(idx<N) curs[idx]+=bsum[blockIdx.x];
}

__global__ void fill_k(const int* __restrict__ dst, int* __restrict__ cursor,
                       int* __restrict__ perm, int E){
    int e=blockIdx.x*blockDim.x+threadIdx.x;
    if(e<E){ int r=atomicAdd(&cursor[dst[e]],1); perm[r]=e; }
}

// XY[n] = [ f@W1[0:64] | f@W1[64:128] ]  (N x 128, bf16)
__global__ __launch_bounds__(256) void xy_mfma(const __bf16* __restrict__ f16,
        const float* __restrict__ W1, __bf16* __restrict__ XY, int N){
    int tid=threadIdx.x, wid=tid>>6, lane=tid&63;
    int q=lane>>4, nn=lane&15;
    bf16x8 Bf[2][8];
    #pragma unroll
    for(int s=0;s<2;++s)
        #pragma unroll
        for(int ng=0;ng<8;++ng){
            bf16x8 t;
            #pragma unroll
            for(int j=0;j<8;++j){
                int k=32*s+8*q+j, c=16*ng+nn;
                float v = (c<64) ? W1[k*64+c] : W1[(64+k)*64 + (c-64)];
                t[j]=(__bf16)v;
            }
            Bf[s][ng]=t;
        }
    int ntiles=(N+15)/16;
    int gw=gridDim.x*4;
    for(int t=blockIdx.x*4+wid; t<ntiles; t+=gw){
        int row=t*16+nn; if(row>=N) row=N-1;
        bf16x8 a0=*(const bf16x8*)&f16[(size_t)row*64 + 8*q];
        bf16x8 a1=*(const bf16x8*)&f16[(size_t)row*64 + 32 + 8*q];
        #pragma unroll
        for(int ng=0;ng<8;++ng){
            f32x4 acc; acc[0]=0.f; acc[1]=0.f; acc[2]=0.f; acc[3]=0.f;
            acc=__builtin_amdgcn_mfma_f32_16x16x32_bf16(a0,Bf[0][ng],acc,0,0,0);
            acc=__builtin_amdgcn_mfma_f32_16x16x32_bf16(a1,Bf[1][ng],acc,0,0,0);
            #pragma unroll
            for(int r=0;r<4;++r){
                int orow=t*16+4*q+r;
                if(orow<N) XY[(size_t)orow*128 + 16*ng + nn]=(__bf16)acc[r];
            }
        }
    }
}

// edge kernel: h1 = silu(X[src]+Y[dst]+w^2*W1[128]+b1) in A-frag regs, GEMM2 MFMA,
// gated, segmented scatter over dst-sorted 32-slot tiles.
__global__ __launch_bounds__(256) void edge_mfma2(
        const __bf16* __restrict__ XY,
        const float* __restrict__ w, const int* __restrict__ src, const int* __restrict__ dst,
        const int* __restrict__ perm,
        const float* __restrict__ W1, const float* __restrict__ b1,
        const float* __restrict__ W2, const float* __restrict__ b2,
        float* __restrict__ msum, int E){
    int tid=threadIdx.x, wid=tid>>6, lane=tid&63;
    int q=lane>>4, nn=lane&15;

    bf16x8 B2f[2][4];
    #pragma unroll
    for(int s=0;s<2;++s)
        #pragma unroll
        for(int ng=0;ng<4;++ng){
            bf16x8 t;
            #pragma unroll
            for(int j=0;j<8;++j) t[j]=(__bf16)W2[(32*s+8*q+j)*64 + 16*ng + nn];
            B2f[s][ng]=t;
        }
    float w128lo[8], w128hi[8], b1lo[8], b1hi[8];
    #pragma unroll
    for(int j=0;j<8;++j){
        w128lo[j]=W1[128*64 + 8*q+j];
        w128hi[j]=W1[128*64 + 32+8*q+j];
        b1lo[j]=b1[8*q+j];
        b1hi[j]=b1[32+8*q+j];
    }
    float bias2[4];
    #pragma unroll
    for(int ng=0;ng<4;++ng) bias2[ng]=b2[16*ng+nn];

    __shared__ float sm[4][32][68];

    int ntiles=E/32;
    int gw=gridDim.x*4;
    for(int t=blockIdx.x*4+wid; t<ntiles; t+=gw){
        int slot=t*32+lane;
        int d_=-1, s_=0; float w2v=0.f;
        if(lane<32){
            int eid=perm[slot];
            s_=src[eid]; d_=dst[eid];
            float ww=w[eid]; w2v=ww*ww;
        }
        #pragma unroll
        for(int h=0;h<2;++h){
            int se=__shfl(s_, 16*h+nn, 64);
            int de=__shfl(d_, 16*h+nn, 64);
            float w2=__shfl(w2v, 16*h+nn, 64);
            const __bf16* xp = XY + (size_t)se*128;
            const __bf16* yp = XY + (size_t)de*128 + 64;
            bf16x8 xlo=*(const bf16x8*)(xp + 8*q);
            bf16x8 xhi=*(const bf16x8*)(xp + 32 + 8*q);
            bf16x8 ylo=*(const bf16x8*)(yp + 8*q);
            bf16x8 yhi=*(const bf16x8*)(yp + 32 + 8*q);
            bf16x8 a20, a21;
            #pragma unroll
            for(int j=0;j<8;++j){
                float hlo=(float)xlo[j] + (float)ylo[j] + w2*w128lo[j] + b1lo[j];
                float hhi=(float)xhi[j] + (float)yhi[j] + w2*w128hi[j] + b1hi[j];
                a20[j]=(__bf16)silu_f(hlo);
                a21[j]=(__bf16)silu_f(hhi);
            }
            f32x4 acc2[4];
            #pragma unroll
            for(int ng=0;ng<4;++ng){ f32x4 c; c[0]=bias2[ng]; c[1]=bias2[ng]; c[2]=bias2[ng]; c[3]=bias2[ng]; acc2[ng]=c; }
            #pragma unroll
            for(int ng=0;ng<4;++ng){
                acc2[ng]=__builtin_amdgcn_mfma_f32_16x16x32_bf16(a20,B2f[0][ng],acc2[ng],0,0,0);
                acc2[ng]=__builtin_amdgcn_mfma_f32_16x16x32_bf16(a21,B2f[1][ng],acc2[ng],0,0,0);
            }
            #pragma unroll
            for(int ng=0;ng<4;++ng)
                #pragma unroll
                for(int r=0;r<4;++r)
                    sm[wid][16*h+4*q+r][16*ng+nn]=silu_f(silu_f(acc2[ng][r]));
        }
        asm volatile("" ::: "memory");
        float vsum=0.f; int cur=__shfl(d_, 0, 64);
        #pragma unroll
        for(int r=0;r<32;++r){
            int dr=__shfl(d_, r, 64);
            if(dr!=cur){
                if(cur>=0) atomicAdd(&msum[(size_t)cur*64+lane], vsum);
                vsum=0.f; cur=dr;
            }
            vsum+=sm[wid][r][lane];
        }
        if(cur>=0) atomicAdd(&msum[(size_t)cur*64+lane], vsum);
        asm volatile("" ::: "memory");
    }
}

// node 2-layer MLP via MFMA: out = silu((A[+F])@W1+b1)@W2+b2 [+F]
__global__ __launch_bounds__(256) void node_mfma(const float* __restrict__ A, const float* __restrict__ F,
        const float* __restrict__ W1, const float* __restrict__ b1,
        const float* __restrict__ W2, const float* __restrict__ b2,
        float* __restrict__ out, __bf16* __restrict__ out16, int N){
    int tid=threadIdx.x, wid=tid>>6, lane=tid&63;
    int q=lane>>4, nn=lane&15;

    bf16x8 B1f[2][4], B2f[2][4];
    #pragma unroll
    for(int s=0;s<2;++s)
        #pragma unroll
        for(int ng=0;ng<4;++ng){
            bf16x8 t1, t2;
            #pragma unroll
            for(int j=0;j<8;++j){
                t1[j]=(__bf16)W1[(32*s+8*q+j)*64 + 16*ng + nn];
                t2[j]=(__bf16)W2[(32*s+8*q+j)*64 + 16*ng + nn];
            }
            B1f[s][ng]=t1; B2f[s][ng]=t2;
        }
    float bias1[4], bias2[4];
    #pragma unroll
    for(int ng=0;ng<4;++ng){ bias1[ng]=b1[16*ng+nn]; bias2[ng]=b2[16*ng+nn]; }

    __shared__ __align__(16) __bf16 sh1[4][16][72];
    __shared__ __align__(16) float sF[4][16][68];
    bool hasF = (F != nullptr);

    int ntiles=(N+15)/16;
    int gw=gridDim.x*4;
    for(int t=blockIdx.x*4+wid; t<ntiles; t+=gw){
        int m=t*16+nn;
        int mc=(m<N)?m:(N-1);
        float4 a0=*(const float4*)&A[(size_t)mc*64 + 8*q];
        float4 a1=*(const float4*)&A[(size_t)mc*64 + 8*q + 4];
        float4 a2=*(const float4*)&A[(size_t)mc*64 + 32 + 8*q];
        float4 a3=*(const float4*)&A[(size_t)mc*64 + 32 + 8*q + 4];
        if(hasF){
            float4 f0=*(const float4*)&F[(size_t)mc*64 + 8*q];
            float4 f1=*(const float4*)&F[(size_t)mc*64 + 8*q + 4];
            float4 f2_=*(const float4*)&F[(size_t)mc*64 + 32 + 8*q];
            float4 f3=*(const float4*)&F[(size_t)mc*64 + 32 + 8*q + 4];
            a0.x+=f0.x; a0.y+=f0.y; a0.z+=f0.z; a0.w+=f0.w;
            a1.x+=f1.x; a1.y+=f1.y; a1.z+=f1.z; a1.w+=f1.w;
            a2.x+=f2_.x; a2.y+=f2_.y; a2.z+=f2_.z; a2.w+=f2_.w;
            a3.x+=f3.x; a3.y+=f3.y; a3.z+=f3.z; a3.w+=f3.w;
            *(float4*)&sF[wid][nn][8*q]   = f0;
            *(float4*)&sF[wid][nn][8*q+4] = f1;
            *(float4*)&sF[wid][nn][32+8*q]   = f2_;
            *(float4*)&sF[wid][nn][32+8*q+4] = f3;
        }
        bf16x8 af0, af1;
        af0[0]=(__bf16)a0.x; af0[1]=(__bf16)a0.y; af0[2]=(__bf16)a0.z; af0[3]=(__bf16)a0.w;
        af0[4]=(__bf16)a1.x; af0[5]=(__bf16)a1.y; af0[6]=(__bf16)a1.z; af0[7]=(__bf16)a1.w;
        af1[0]=(__bf16)a2.x; af1[1]=(__bf16)a2.y; af1[2]=(__bf16)a2.z; af1[3]=(__bf16)a2.w;
        af1[4]=(__bf16)a3.x; af1[5]=(__bf16)a3.y; af1[6]=(__bf16)a3.z; af1[7]=(__bf16)a3.w;

        f32x4 acc[4];
        #pragma unroll
        for(int ng=0;ng<4;++ng){ f32x4 c; c[0]=bias1[ng]; c[1]=bias1[ng]; c[2]=bias1[ng]; c[3]=bias1[ng]; acc[ng]=c; }
        #pragma unroll
        for(int ng=0;ng<4;++ng){
            acc[ng]=__builtin_amdgcn_mfma_f32_16x16x32_bf16(af0,B1f[0][ng],acc[ng],0,0,0);
            acc[ng]=__builtin_amdgcn_mfma_f32_16x16x32_bf16(af1,B1f[1][ng],acc[ng],0,0,0);
        }
        #pragma unroll
        for(int ng=0;ng<4;++ng)
            #pragma unroll
            for(int r=0;r<4;++r)
                sh1[wid][4*q+r][16*ng+nn]=(__bf16)silu_f(acc[ng][r]);
        asm volatile("" ::: "memory");
        bf16x8 a20=*(const bf16x8*)&sh1[wid][nn][8*q];
        bf16x8 a21=*(const bf16x8*)&sh1[wid][nn][32+8*q];
        f32x4 acc2[4];
        #pragma unroll
        for(int ng=0;ng<4;++ng){ f32x4 c; c[0]=bias2[ng]; c[1]=bias2[ng]; c[2]=bias2[ng]; c[3]=bias2[ng]; acc2[ng]=c; }
        #pragma unroll
        for(int ng=0;ng<4;++ng){
            acc2[ng]=__builtin_amdgcn_mfma_f32_16x16x32_bf16(a20,B2f[0][ng],acc2[ng],0,0,0);
            acc2[ng]=__builtin_amdgcn_mfma_f32_16x16x32_bf16(a21,B2f[1][ng],acc2[ng],0,0,0);
        }
        #pragma unroll
        for(int ng=0;ng<4;++ng)
            #pragma unroll
            for(int r=0;r<4;++r){
                int row=t*16+4*q+r;
                if(row<N){
                    float o=acc2[ng][r];
                    if(hasF) o += sF[wid][4*q+r][16*ng+nn];
                    out[(size_t)row*64 + 16*ng + nn]=o;
                    if(out16) out16[(size_t)row*64 + 16*ng + nn]=(__bf16)o;
                }
            }
        asm volatile("" ::: "memory");
    }
}

__global__ __launch_bounds__(256) void seg_reduce_sorted(const float* __restrict__ f2, const int* __restrict__ gid,
        float* __restrict__ gsum, unsigned* __restrict__ gmaxu, float* __restrict__ cnt, int N){
    int wgl=blockIdx.x*4 + (threadIdx.x>>6);
    int lane=threadIdx.x&63;
    int W=gridDim.x*4;
    int chunk=(N+W-1)/W;
    int n0=wgl*chunk;
    int n1=n0+chunk; if(n1>N) n1=N;
    if(n0>=n1) return;
    int cur=gid[n0];
    float s=0.f, mx=-__builtin_inff(), c=0.f;
    for(int n=n0;n<n1;++n){
        int g=gid[n];
        float v=f2[(size_t)n*64+lane];
        if(g!=cur){
            atomicAdd(&gsum[(size_t)cur*64+lane], s);
            atomicMax(&gmaxu[(size_t)cur*64+lane], fenc(mx));
            if(lane==0) atomicAdd(&cnt[cur], c);
            s=0.f; mx=-__builtin_inff(); c=0.f; cur=g;
        }
        s+=v; mx=fmaxf(mx,v); c+=1.f;
    }
    atomicAdd(&gsum[(size_t)cur*64+lane], s);
    atomicMax(&gmaxu[(size_t)cur*64+lane], fenc(mx));
    if(lane==0) atomicAdd(&cnt[cur], c);
}

__global__ __launch_bounds__(256) void readout_k(const float* __restrict__ gsum, const unsigned* __restrict__ gmaxu,
        const float* __restrict__ cnt,
        const float* __restrict__ W1, const float* __restrict__ b1,
        const float* __restrict__ W2, const float* __restrict__ b2,
        float* __restrict__ out, int G){
    __shared__ __align__(16) float sr[4][192];
    int tid=threadIdx.x, wid=tid>>6, lane=tid&63;
    int g=blockIdx.x*4+wid;
    if(g<G){
        float s_=gsum[g*64+lane];
        float c=cnt[g];
        float mean=s_/fmaxf(c,1.0f);
        float mx=fdec(gmaxu[g*64+lane]);
        sr[wid][lane]=s_; sr[wid][64+lane]=mean; sr[wid][128+lane]=mx;
    }
    __syncthreads();
    if(g<G){
        float h=b1[lane];
        for(int k=0;k<192;k+=4){
            float4 r4=*(const float4*)&sr[wid][k];
            h += r4.x*W1[(k+0)*64+lane] + r4.y*W1[(k+1)*64+lane]
               + r4.z*W1[(k+2)*64+lane] + r4.w*W1[(k+3)*64+lane];
        }
        h=silu_f(h);
        float p=h*W2[lane];
        #pragma unroll
        for(int off=32;off>0;off>>=1) p += __shfl_down(p, off, 64);
        if(lane==0) out[g]=p+b2[0];
    }
}

extern "C" void kernel_launch(void* const* d_in, const int* in_sizes, int n_in,
                              void* d_out, int out_size, void* d_ws, size_t ws_size,
                              hipStream_t stream){
    const float* x     = (const float*)d_in[0];
    const float* w     = (const float*)d_in[1];
    const int*   src   = (const int*)d_in[2];
    const int*   dst   = (const int*)d_in[3];
    const int*   gid   = (const int*)d_in[4];
    const float* W_in  = (const float*)d_in[5];
    const float* b_in  = (const float*)d_in[6];
    const float* msgW1 = (const float*)d_in[7];
    const float* msgb1 = (const float*)d_in[8];
    const float* msgW2 = (const float*)d_in[9];
    const float* msgb2 = (const float*)d_in[10];
    const float* updW1 = (const float*)d_in[11];
    const float* updb1 = (const float*)d_in[12];
    const float* updW2 = (const float*)d_in[13];
    const float* updb2 = (const float*)d_in[14];
    const float* outW1 = (const float*)d_in[15];
    const float* outb1 = (const float*)d_in[16];
    const float* outW2 = (const float*)d_in[17];
    const float* outb2 = (const float*)d_in[18];
    const float* roW1  = (const float*)d_in[19];
    const float* rob1  = (const float*)d_in[20];
    const float* roW2  = (const float*)d_in[21];
    const float* rob2  = (const float*)d_in[22];

    float*  f     = (float*)d_ws;                         // N*64 f32
    float*  msum  = f + (size_t)NN*64;                    // N*64 f32 (reused as f2)
    float*  f2    = msum;
    __bf16* f16   = (__bf16*)(msum + (size_t)NN*64);      // N*64 bf16
    __bf16* XY    = f16 + (size_t)NN*64;                  // N*128 bf16
    int*    perm  = (int*)(XY + (size_t)NN*128);          // E
    int*    deg   = perm + EE;                            // N (padded)
    int*    curs  = deg + 50048;                          // N (padded)
    int*    bsum  = curs + 50048;                         // SCAN_B (padded 256)
    float*  gsum  = (float*)(bsum + 256);                 // G*64
    unsigned* gmaxu = (unsigned*)(gsum + GG*64);          // G*64
    float*  cnt   = (float*)(gmaxu + GG*64);              // G

    hipMemsetAsync(deg, 0, 50048*sizeof(int), stream);
    hist_k<<<dim3((EE+255)/256),dim3(256),0,stream>>>(dst, deg, EE);
    scan1_k<<<dim3(SCAN_B),dim3(256),0,stream>>>(deg, curs, bsum, NN);
    scan2_k<<<dim3(1),dim3(256),0,stream>>>(bsum, SCAN_B);
    scan3_k<<<dim3(SCAN_B),dim3(256),0,stream>>>(curs, bsum, NN);
    fill_k<<<dim3((EE+255)/256),dim3(256),0,stream>>>(dst, curs, perm, EE);

    input_mlp<<<dim3(1024),dim3(256),0,stream>>>(x, W_in, b_in, f, f16, NN);
    for(int l=0;l<LL;++l){
        xy_mfma<<<dim3(512),dim3(256),0,stream>>>(f16, msgW1 + (size_t)l*129*64, XY, NN);
        hipMemsetAsync(msum, 0, (size_t)NN*64*sizeof(float), stream);
        edge_mfma2<<<dim3(1024),dim3(256),0,stream>>>(XY, w, src, dst, perm,
            msgW1 + (size_t)l*129*64, msgb1 + l*64,
            msgW2 + (size_t)l*64*64,  msgb2 + l*64, msum, EE);
        node_mfma<<<dim3(782),dim3(256),0,stream>>>(msum, f,
            updW1 + (size_t)l*64*64, updb1 + l*64,
            updW2 + (size_t)l*64*64, updb2 + l*64, f, f16, NN);
    }
    node_mfma<<<dim3(782),dim3(256),0,stream>>>(f, nullptr, outW1, outb1, outW2, outb2, f2, nullptr, NN);
    hipMemsetAsync(gsum, 0, (size_t)(GG*64*2 + GG)*sizeof(float), stream);
    seg_reduce_sorted<<<dim3(256),dim3(256),0,stream>>>(f2, gid, gsum, gmaxu, cnt, NN);
    readout_k<<<dim3(32),dim3(256),0,stream>>>(gsum, gmaxu, cnt, roW1, rob1, roW2, rob2, (float*)d_out, GG);
}

// Round 6
// 669.025 us; speedup vs baseline: 11.5995x; 1.0619x over previous
//
#include <hip/hip_runtime.h>

#define NN 50000
#define EE 800000
#define GG 128
#define LL 4
#define SCAN_B 196   // ceil(50048/256)

typedef __bf16 bf16x8 __attribute__((ext_vector_type(8)));
typedef float  f32x4  __attribute__((ext_vector_type(4)));

// fast silu: x * rcp(1 + 2^(-x*log2e))
__device__ __forceinline__ float silu_f(float x){
    float t = __builtin_amdgcn_exp2f(-1.44269504f * x);
    return x * __builtin_amdgcn_rcpf(1.0f + t);
}
__device__ __forceinline__ unsigned fenc(float v){
    unsigned u = __float_as_uint(v);
    return (u & 0x80000000u) ? ~u : (u | 0x80000000u);
}
__device__ __forceinline__ float fdec(unsigned u){
    return (u & 0x80000000u) ? __uint_as_float(u & 0x7fffffffu) : __uint_as_float(~u);
}

__global__ __launch_bounds__(256) void input_mlp(const float* __restrict__ x,
        const float* __restrict__ Wg, const float* __restrict__ bg,
        float* __restrict__ f, __bf16* __restrict__ f16, int N){
    __shared__ __align__(16) float sW[64*64];
    __shared__ float sb[64];
    __shared__ __align__(16) float srow[4][64];
    int tid=threadIdx.x, wid=tid>>6, lane=tid&63;
    for(int i=tid;i<4096;i+=256) sW[i]=Wg[i];
    if(tid<64) sb[tid]=bg[tid];
    __syncthreads();
    int gw=gridDim.x*4;
    int n0=blockIdx.x*4+wid;
    int niter=(N+gw-1)/gw;
    for(int it=0;it<niter;++it){
        int n=n0+it*gw; bool act = n<N;
        if(act) srow[wid][lane]=x[n*64+lane];
        __syncthreads();
        if(act){
            float h=sb[lane];
            #pragma unroll
            for(int k=0;k<64;k+=4){
                float4 m4=*(const float4*)&srow[wid][k];
                h += m4.x*sW[k*64+lane] + m4.y*sW[(k+1)*64+lane]
                   + m4.z*sW[(k+2)*64+lane] + m4.w*sW[(k+3)*64+lane];
            }
            float o=silu_f(h);
            f[n*64+lane]=o; f16[n*64+lane]=(__bf16)o;
        }
        __syncthreads();
    }
}

__global__ void hist_k(const int* __restrict__ dst, int* __restrict__ deg, int E){
    int e=blockIdx.x*blockDim.x+threadIdx.x;
    if(e<E) atomicAdd(&deg[dst[e]],1);
}

// ---- 3-pass parallel exclusive scan ----
__global__ __launch_bounds__(256) void scan1_k(const int* __restrict__ deg, int* __restrict__ curs,
        int* __restrict__ bsum, int N){
    __shared__ int sv[256];
    int tid=threadIdx.x;
    int idx=blockIdx.x*256+tid;
    int v=(idx<N)?deg[idx]:0;
    sv[tid]=v; __syncthreads();
    #pragma unroll
    for(int off=1; off<256; off<<=1){
        int a=(tid>=off)?sv[tid-off]:0;
        __syncthreads(); sv[tid]+=a; __syncthreads();
    }
    if(idx<N) curs[idx]=sv[tid]-v;
    if(tid==255) bsum[blockIdx.x]=sv[255];
}
__global__ __launch_bounds__(256) void scan2_k(int* __restrict__ bsum, int B){
    __shared__ int sv[256];
    int tid=threadIdx.x;
    int v=(tid<B)?bsum[tid]:0;
    sv[tid]=v; __syncthreads();
    #pragma unroll
    for(int off=1; off<256; off<<=1){
        int a=(tid>=off)?sv[tid-off]:0;
        __syncthreads(); sv[tid]+=a; __syncthreads();
    }
    if(tid<B) bsum[tid]=sv[tid]-v;
}
__global__ __launch_bounds__(256) void scan3_k(int* __restrict__ curs, const int* __restrict__ bsum, int N){
    int idx=blockIdx.x*256+threadIdx.x;
    if(idx<N) curs[idx]+=bsum[blockIdx.x];
}

// rank-scatter: emit slot-ordered metadata directly (no perm indirection later)
__global__ void fill_k(const int* __restrict__ src, const int* __restrict__ dst,
                       const float* __restrict__ w, int* __restrict__ cursor,
                       int* __restrict__ src_s, int* __restrict__ dst_s,
                       float* __restrict__ w2_s, int E){
    int e=blockIdx.x*blockDim.x+threadIdx.x;
    if(e<E){
        int d=dst[e];
        int r=atomicAdd(&cursor[d],1);
        src_s[r]=src[e];
        dst_s[r]=d;
        float ww=w[e];
        w2_s[r]=ww*ww;
    }
}

// XY[n] = [ f@W1[0:64] | f@W1[64:128] ]  (N x 128, bf16)
__global__ __launch_bounds__(256) void xy_mfma(const __bf16* __restrict__ f16,
        const float* __restrict__ W1, __bf16* __restrict__ XY, int N){
    int tid=threadIdx.x, wid=tid>>6, lane=tid&63;
    int q=lane>>4, nn=lane&15;
    bf16x8 Bf[2][8];
    #pragma unroll
    for(int s=0;s<2;++s)
        #pragma unroll
        for(int ng=0;ng<8;++ng){
            bf16x8 t;
            #pragma unroll
            for(int j=0;j<8;++j){
                int k=32*s+8*q+j, c=16*ng+nn;
                float v = (c<64) ? W1[k*64+c] : W1[(64+k)*64 + (c-64)];
                t[j]=(__bf16)v;
            }
            Bf[s][ng]=t;
        }
    int ntiles=(N+15)/16;
    int gw=gridDim.x*4;
    for(int t=blockIdx.x*4+wid; t<ntiles; t+=gw){
        int row=t*16+nn; if(row>=N) row=N-1;
        bf16x8 a0=*(const bf16x8*)&f16[(size_t)row*64 + 8*q];
        bf16x8 a1=*(const bf16x8*)&f16[(size_t)row*64 + 32 + 8*q];
        #pragma unroll
        for(int ng=0;ng<8;++ng){
            f32x4 acc; acc[0]=0.f; acc[1]=0.f; acc[2]=0.f; acc[3]=0.f;
            acc=__builtin_amdgcn_mfma_f32_16x16x32_bf16(a0,Bf[0][ng],acc,0,0,0);
            acc=__builtin_amdgcn_mfma_f32_16x16x32_bf16(a1,Bf[1][ng],acc,0,0,0);
            #pragma unroll
            for(int r=0;r<4;++r){
                int orow=t*16+4*q+r;
                if(orow<N) XY[(size_t)orow*128 + 16*ng + nn]=(__bf16)acc[r];
            }
        }
    }
}

// edge kernel: slot-ordered metadata (coalesced), h1 in A-frag regs, GEMM2 MFMA,
// gated, segmented scatter over dst-sorted 32-slot tiles.
__global__ __launch_bounds__(256) void edge_mfma2(
        const __bf16* __restrict__ XY,
        const int* __restrict__ src_s, const int* __restrict__ dst_s,
        const float* __restrict__ w2_s,
        const float* __restrict__ W1, const float* __restrict__ b1,
        const float* __restrict__ W2, const float* __restrict__ b2,
        float* __restrict__ msum, int E){
    int tid=threadIdx.x, wid=tid>>6, lane=tid&63;
    int q=lane>>4, nn=lane&15;

    bf16x8 B2f[2][4];
    #pragma unroll
    for(int s=0;s<2;++s)
        #pragma unroll
        for(int ng=0;ng<4;++ng){
            bf16x8 t;
            #pragma unroll
            for(int j=0;j<8;++j) t[j]=(__bf16)W2[(32*s+8*q+j)*64 + 16*ng + nn];
            B2f[s][ng]=t;
        }
    float w128lo[8], w128hi[8], b1lo[8], b1hi[8];
    #pragma unroll
    for(int j=0;j<8;++j){
        w128lo[j]=W1[128*64 + 8*q+j];
        w128hi[j]=W1[128*64 + 32+8*q+j];
        b1lo[j]=b1[8*q+j];
        b1hi[j]=b1[32+8*q+j];
    }
    float bias2[4];
    #pragma unroll
    for(int ng=0;ng<4;++ng) bias2[ng]=b2[16*ng+nn];

    __shared__ float sm[4][32][68];

    int ntiles=E/32;
    int gw=gridDim.x*4;
    for(int t=blockIdx.x*4+wid; t<ntiles; t+=gw){
        int slot=t*32+lane;
        int d_=-1, s_=0; float w2v=0.f;
        if(lane<32){
            s_=src_s[slot];
            d_=dst_s[slot];
            w2v=w2_s[slot];
        }
        #pragma unroll
        for(int h=0;h<2;++h){
            int se=__shfl(s_, 16*h+nn, 64);
            int de=__shfl(d_, 16*h+nn, 64);
            float w2=__shfl(w2v, 16*h+nn, 64);
            const __bf16* xp = XY + (size_t)se*128;
            const __bf16* yp = XY + (size_t)de*128 + 64;
            bf16x8 xlo=*(const bf16x8*)(xp + 8*q);
            bf16x8 xhi=*(const bf16x8*)(xp + 32 + 8*q);
            bf16x8 ylo=*(const bf16x8*)(yp + 8*q);
            bf16x8 yhi=*(const bf16x8*)(yp + 32 + 8*q);
            bf16x8 a20, a21;
            #pragma unroll
            for(int j=0;j<8;++j){
                float hlo=(float)xlo[j] + (float)ylo[j] + w2*w128lo[j] + b1lo[j];
                float hhi=(float)xhi[j] + (float)yhi[j] + w2*w128hi[j] + b1hi[j];
                a20[j]=(__bf16)silu_f(hlo);
                a21[j]=(__bf16)silu_f(hhi);
            }
            f32x4 acc2[4];
            #pragma unroll
            for(int ng=0;ng<4;++ng){ f32x4 c; c[0]=bias2[ng]; c[1]=bias2[ng]; c[2]=bias2[ng]; c[3]=bias2[ng]; acc2[ng]=c; }
            #pragma unroll
            for(int ng=0;ng<4;++ng){
                acc2[ng]=__builtin_amdgcn_mfma_f32_16x16x32_bf16(a20,B2f[0][ng],acc2[ng],0,0,0);
                acc2[ng]=__builtin_amdgcn_mfma_f32_16x16x32_bf16(a21,B2f[1][ng],acc2[ng],0,0,0);
            }
            #pragma unroll
            for(int ng=0;ng<4;++ng)
                #pragma unroll
                for(int r=0;r<4;++r)
                    sm[wid][16*h+4*q+r][16*ng+nn]=silu_f(silu_f(acc2[ng][r]));
        }
        asm volatile("" ::: "memory");
        float vsum=0.f; int cur=__shfl(d_, 0, 64);
        #pragma unroll
        for(int r=0;r<32;++r){
            int dr=__shfl(d_, r, 64);
            if(dr!=cur){
                atomicAdd(&msum[(size_t)cur*64+lane], vsum);
                vsum=0.f; cur=dr;
            }
            vsum+=sm[wid][r][lane];
        }
        atomicAdd(&msum[(size_t)cur*64+lane], vsum);
        asm volatile("" ::: "memory");
    }
}

// node 2-layer MLP via MFMA: out = silu((A[+F])@W1+b1)@W2+b2 [+F]
__global__ __launch_bounds__(256) void node_mfma(const float* __restrict__ A, const float* __restrict__ F,
        const float* __restrict__ W1, const float* __restrict__ b1,
        const float* __restrict__ W2, const float* __restrict__ b2,
        float* __restrict__ out, __bf16* __restrict__ out16, int N){
    int tid=threadIdx.x, wid=tid>>6, lane=tid&63;
    int q=lane>>4, nn=lane&15;

    bf16x8 B1f[2][4], B2f[2][4];
    #pragma unroll
    for(int s=0;s<2;++s)
        #pragma unroll
        for(int ng=0;ng<4;++ng){
            bf16x8 t1, t2;
            #pragma unroll
            for(int j=0;j<8;++j){
                t1[j]=(__bf16)W1[(32*s+8*q+j)*64 + 16*ng + nn];
                t2[j]=(__bf16)W2[(32*s+8*q+j)*64 + 16*ng + nn];
            }
            B1f[s][ng]=t1; B2f[s][ng]=t2;
        }
    float bias1[4], bias2[4];
    #pragma unroll
    for(int ng=0;ng<4;++ng){ bias1[ng]=b1[16*ng+nn]; bias2[ng]=b2[16*ng+nn]; }

    __shared__ __align__(16) __bf16 sh1[4][16][72];
    __shared__ __align__(16) float sF[4][16][68];
    bool hasF = (F != nullptr);

    int ntiles=(N+15)/16;
    int gw=gridDim.x*4;
    for(int t=blockIdx.x*4+wid; t<ntiles; t+=gw){
        int m=t*16+nn;
        int mc=(m<N)?m:(N-1);
        float4 a0=*(const float4*)&A[(size_t)mc*64 + 8*q];
        float4 a1=*(const float4*)&A[(size_t)mc*64 + 8*q + 4];
        float4 a2=*(const float4*)&A[(size_t)mc*64 + 32 + 8*q];
        float4 a3=*(const float4*)&A[(size_t)mc*64 + 32 + 8*q + 4];
        if(hasF){
            float4 f0=*(const float4*)&F[(size_t)mc*64 + 8*q];
            float4 f1=*(const float4*)&F[(size_t)mc*64 + 8*q + 4];
            float4 f2_=*(const float4*)&F[(size_t)mc*64 + 32 + 8*q];
            float4 f3=*(const float4*)&F[(size_t)mc*64 + 32 + 8*q + 4];
            a0.x+=f0.x; a0.y+=f0.y; a0.z+=f0.z; a0.w+=f0.w;
            a1.x+=f1.x; a1.y+=f1.y; a1.z+=f1.z; a1.w+=f1.w;
            a2.x+=f2_.x; a2.y+=f2_.y; a2.z+=f2_.z; a2.w+=f2_.w;
            a3.x+=f3.x; a3.y+=f3.y; a3.z+=f3.z; a3.w+=f3.w;
            *(float4*)&sF[wid][nn][8*q]   = f0;
            *(float4*)&sF[wid][nn][8*q+4] = f1;
            *(float4*)&sF[wid][nn][32+8*q]   = f2_;
            *(float4*)&sF[wid][nn][32+8*q+4] = f3;
        }
        bf16x8 af0, af1;
        af0[0]=(__bf16)a0.x; af0[1]=(__bf16)a0.y; af0[2]=(__bf16)a0.z; af0[3]=(__bf16)a0.w;
        af0[4]=(__bf16)a1.x; af0[5]=(__bf16)a1.y; af0[6]=(__bf16)a1.z; af0[7]=(__bf16)a1.w;
        af1[0]=(__bf16)a2.x; af1[1]=(__bf16)a2.y; af1[2]=(__bf16)a2.z; af1[3]=(__bf16)a2.w;
        af1[4]=(__bf16)a3.x; af1[5]=(__bf16)a3.y; af1[6]=(__bf16)a3.z; af1[7]=(__bf16)a3.w;

        f32x4 acc[4];
        #pragma unroll
        for(int ng=0;ng<4;++ng){ f32x4 c; c[0]=bias1[ng]; c[1]=bias1[ng]; c[2]=bias1[ng]; c[3]=bias1[ng]; acc[ng]=c; }
        #pragma unroll
        for(int ng=0;ng<4;++ng){
            acc[ng]=__builtin_amdgcn_mfma_f32_16x16x32_bf16(af0,B1f[0][ng],acc[ng],0,0,0);
            acc[ng]=__builtin_amdgcn_mfma_f32_16x16x32_bf16(af1,B1f[1][ng],acc[ng],0,0,0);
        }
        #pragma unroll
        for(int ng=0;ng<4;++ng)
            #pragma unroll
            for(int r=0;r<4;++r)
                sh1[wid][4*q+r][16*ng+nn]=(__bf16)silu_f(acc[ng][r]);
        asm volatile("" ::: "memory");
        bf16x8 a20=*(const bf16x8*)&sh1[wid][nn][8*q];
        bf16x8 a21=*(const bf16x8*)&sh1[wid][nn][32+8*q];
        f32x4 acc2[4];
        #pragma unroll
        for(int ng=0;ng<4;++ng){ f32x4 c; c[0]=bias2[ng]; c[1]=bias2[ng]; c[2]=bias2[ng]; c[3]=bias2[ng]; acc2[ng]=c; }
        #pragma unroll
        for(int ng=0;ng<4;++ng){
            acc2[ng]=__builtin_amdgcn_mfma_f32_16x16x32_bf16(a20,B2f[0][ng],acc2[ng],0,0,0);
            acc2[ng]=__builtin_amdgcn_mfma_f32_16x16x32_bf16(a21,B2f[1][ng],acc2[ng],0,0,0);
        }
        #pragma unroll
        for(int ng=0;ng<4;++ng)
            #pragma unroll
            for(int r=0;r<4;++r){
                int row=t*16+4*q+r;
                if(row<N){
                    float o=acc2[ng][r];
                    if(hasF) o += sF[wid][4*q+r][16*ng+nn];
                    out[(size_t)row*64 + 16*ng + nn]=o;
                    if(out16) out16[(size_t)row*64 + 16*ng + nn]=(__bf16)o;
                }
            }
        asm volatile("" ::: "memory");
    }
}

__global__ __launch_bounds__(256) void seg_reduce_sorted(const float* __restrict__ f2, const int* __restrict__ gid,
        float* __restrict__ gsum, unsigned* __restrict__ gmaxu, float* __restrict__ cnt, int N){
    int wgl=blockIdx.x*4 + (threadIdx.x>>6);
    int lane=threadIdx.x&63;
    int W=gridDim.x*4;
    int chunk=(N+W-1)/W;
    int n0=wgl*chunk;
    int n1=n0+chunk; if(n1>N) n1=N;
    if(n0>=n1) return;
    int cur=gid[n0];
    float s=0.f, mx=-__builtin_inff(), c=0.f;
    for(int n=n0;n<n1;++n){
        int g=gid[n];
        float v=f2[(size_t)n*64+lane];
        if(g!=cur){
            atomicAdd(&gsum[(size_t)cur*64+lane], s);
            atomicMax(&gmaxu[(size_t)cur*64+lane], fenc(mx));
            if(lane==0) atomicAdd(&cnt[cur], c);
            s=0.f; mx=-__builtin_inff(); c=0.f; cur=g;
        }
        s+=v; mx=fmaxf(mx,v); c+=1.f;
    }
    atomicAdd(&gsum[(size_t)cur*64+lane], s);
    atomicMax(&gmaxu[(size_t)cur*64+lane], fenc(mx));
    if(lane==0) atomicAdd(&cnt[cur], c);
}

__global__ __launch_bounds__(256) void readout_k(const float* __restrict__ gsum, const unsigned* __restrict__ gmaxu,
        const float* __restrict__ cnt,
        const float* __restrict__ W1, const float* __restrict__ b1,
        const float* __restrict__ W2, const float* __restrict__ b2,
        float* __restrict__ out, int G){
    __shared__ __align__(16) float sr[4][192];
    int tid=threadIdx.x, wid=tid>>6, lane=tid&63;
    int g=blockIdx.x*4+wid;
    if(g<G){
        float s_=gsum[g*64+lane];
        float c=cnt[g];
        float mean=s_/fmaxf(c,1.0f);
        float mx=fdec(gmaxu[g*64+lane]);
        sr[wid][lane]=s_; sr[wid][64+lane]=mean; sr[wid][128+lane]=mx;
    }
    __syncthreads();
    if(g<G){
        float h=b1[lane];
        for(int k=0;k<192;k+=4){
            float4 r4=*(const float4*)&sr[wid][k];
            h += r4.x*W1[(k+0)*64+lane] + r4.y*W1[(k+1)*64+lane]
               + r4.z*W1[(k+2)*64+lane] + r4.w*W1[(k+3)*64+lane];
        }
        h=silu_f(h);
        float p=h*W2[lane];
        #pragma unroll
        for(int off=32;off>0;off>>=1) p += __shfl_down(p, off, 64);
        if(lane==0) out[g]=p+b2[0];
    }
}

extern "C" void kernel_launch(void* const* d_in, const int* in_sizes, int n_in,
                              void* d_out, int out_size, void* d_ws, size_t ws_size,
                              hipStream_t stream){
    const float* x     = (const float*)d_in[0];
    const float* w     = (const float*)d_in[1];
    const int*   src   = (const int*)d_in[2];
    const int*   dst   = (const int*)d_in[3];
    const int*   gid   = (const int*)d_in[4];
    const float* W_in  = (const float*)d_in[5];
    const float* b_in  = (const float*)d_in[6];
    const float* msgW1 = (const float*)d_in[7];
    const float* msgb1 = (const float*)d_in[8];
    const float* msgW2 = (const float*)d_in[9];
    const float* msgb2 = (const float*)d_in[10];
    const float* updW1 = (const float*)d_in[11];
    const float* updb1 = (const float*)d_in[12];
    const float* updW2 = (const float*)d_in[13];
    const float* updb2 = (const float*)d_in[14];
    const float* outW1 = (const float*)d_in[15];
    const float* outb1 = (const float*)d_in[16];
    const float* outW2 = (const float*)d_in[17];
    const float* outb2 = (const float*)d_in[18];
    const float* roW1  = (const float*)d_in[19];
    const float* rob1  = (const float*)d_in[20];
    const float* roW2  = (const float*)d_in[21];
    const float* rob2  = (const float*)d_in[22];

    float*  f     = (float*)d_ws;                         // N*64 f32
    float*  msum  = f + (size_t)NN*64;                    // N*64 f32 (reused as f2)
    float*  f2    = msum;
    __bf16* f16   = (__bf16*)(msum + (size_t)NN*64);      // N*64 bf16
    __bf16* XY    = f16 + (size_t)NN*64;                  // N*128 bf16
    int*    src_s = (int*)(XY + (size_t)NN*128);          // E
    int*    dst_s = src_s + EE;                           // E
    float*  w2_s  = (float*)(dst_s + EE);                 // E
    int*    deg   = (int*)(w2_s + EE);                    // N (padded)
    int*    curs  = deg + 50048;                          // N (padded)
    int*    bsum  = curs + 50048;                         // SCAN_B (padded 256)
    float*  gsum  = (float*)(bsum + 256);                 // G*64
    unsigned* gmaxu = (unsigned*)(gsum + GG*64);          // G*64
    float*  cnt   = (float*)(gmaxu + GG*64);              // G

    hipMemsetAsync(deg, 0, 50048*sizeof(int), stream);
    hist_k<<<dim3((EE+255)/256),dim3(256),0,stream>>>(dst, deg, EE);
    scan1_k<<<dim3(SCAN_B),dim3(256),0,stream>>>(deg, curs, bsum, NN);
    scan2_k<<<dim3(1),dim3(256),0,stream>>>(bsum, SCAN_B);
    scan3_k<<<dim3(SCAN_B),dim3(256),0,stream>>>(curs, bsum, NN);
    fill_k<<<dim3((EE+255)/256),dim3(256),0,stream>>>(src, dst, w, curs, src_s, dst_s, w2_s, EE);

    input_mlp<<<dim3(1024),dim3(256),0,stream>>>(x, W_in, b_in, f, f16, NN);
    for(int l=0;l<LL;++l){
        xy_mfma<<<dim3(512),dim3(256),0,stream>>>(f16, msgW1 + (size_t)l*129*64, XY, NN);
        hipMemsetAsync(msum, 0, (size_t)NN*64*sizeof(float), stream);
        edge_mfma2<<<dim3(1024),dim3(256),0,stream>>>(XY, src_s, dst_s, w2_s,
            msgW1 + (size_t)l*129*64, msgb1 + l*64,
            msgW2 + (size_t)l*64*64,  msgb2 + l*64, msum, EE);
        node_mfma<<<dim3(782),dim3(256),0,stream>>>(msum, f,
            updW1 + (size_t)l*64*64, updb1 + l*64,
            updW2 + (size_t)l*64*64, updb2 + l*64, f, f16, NN);
    }
    node_mfma<<<dim3(782),dim3(256),0,stream>>>(f, nullptr, outW1, outb1, outW2, outb2, f2, nullptr, NN);
    hipMemsetAsync(gsum, 0, (size_t)(GG*64*2 + GG)*sizeof(float), stream);
    seg_reduce_sorted<<<dim3(256),dim3(256),0,stream>>>(f2, gid, gsum, gmaxu, cnt, NN);
    readout_k<<<dim3(32),dim3(256),0,stream>>>(gsum, gmaxu, cnt, roW1, rob1, roW2, rob2, (float*)d_out, GG);
}